// Round 7
// baseline (383.543 us; speedup 1.0000x reference)
//
#include <hip/hip_runtime.h>
#include <math.h>

typedef __bf16 bf16x8 __attribute__((ext_vector_type(8)));
typedef __bf16 bf16x4 __attribute__((ext_vector_type(4)));
typedef float f32x4 __attribute__((ext_vector_type(4)));

#define HD 1024
#define SEQ 2048
#define NB 4
#define WEL (HD * HD)   // elements per weight matrix

// Load 8 contiguous elements as bf16x8, converting f32 -> bf16 if needed.
__device__ inline bf16x8 load8cvt(const __bf16* p) { return *(const bf16x8*)p; }
__device__ inline bf16x8 load8cvt(const float* p) {
    f32x4 a = *(const f32x4*)p;
    f32x4 b = *(const f32x4*)(p + 4);
    bf16x8 r;
#pragma unroll
    for (int i = 0; i < 4; ++i) { r[i] = (__bf16)a[i]; r[i + 4] = (__bf16)b[i]; }
    return r;
}

// Load 4 contiguous elements as f32x4 (from f32 or bf16 source).
__device__ inline f32x4 load4f(const float* p) { return *(const f32x4*)p; }
__device__ inline f32x4 load4f(const __bf16* p) {
    bf16x4 v = *(const bf16x4*)p;
    f32x4 r;
#pragma unroll
    for (int i = 0; i < 4; ++i) r[i] = (float)v[i];
    return r;
}

// Async global->LDS, 16 bytes per lane (global_load_lds_dwordx4).
__device__ inline void gld_lds16(const void* g, void* l) {
    __builtin_amdgcn_global_load_lds(
        (const __attribute__((address_space(1))) unsigned int*)g,
        (__attribute__((address_space(3))) unsigned int*)l, 16, 0, 0);
}

// ===========================================================================
// 128x128 BK=64 tile machinery (shared by all GEMMs). XOR-swizzled LDS tile:
// LDS chunk (row, j) holds GLOBAL chunk (row, j ^ (row&7)); global source is
// pre-swizzled so the LDS destination stays linear (global_load_lds rule).
// ===========================================================================
template <typename T>
__device__ inline void stage_tile(const T* __restrict__ G, int ld, __bf16* s, int tid)
{
    const int r  = tid >> 3;                          // 0..31
    const int co = ((tid & 7) ^ (r & 7)) * 8;         // swizzled source column
    if constexpr (sizeof(T) == 2) {
        __bf16* dst = s + (tid >> 6) * 512;           // wave-uniform base
#pragma unroll
        for (int c = 0; c < 4; ++c)
            gld_lds16(G + (long)(c * 32 + r) * ld + co, dst + c * 2048);
    } else {
#pragma unroll
        for (int c = 0; c < 4; ++c)
            *(bf16x8*)(s + c * 2048 + tid * 8) = load8cvt(G + (long)(c * 32 + r) * ld + co);
    }
}

__device__ inline bf16x8 frag_read(const __bf16* s, int row, int c)
{
    return *(const bf16x8*)&s[row * 64 + ((c ^ (row & 7)) * 8)];
}

__device__ inline void mfma_ktile(const __bf16* __restrict__ sa,
                                  const __bf16* __restrict__ sb,
                                  int wm, int wn, int l15, int quad,
                                  f32x4 (&acc)[4][4])
{
#pragma unroll
    for (int kk = 0; kk < 64; kk += 32) {
        const int c8 = quad + (kk >> 3);
        bf16x8 af[4], bf[4];
#pragma unroll
        for (int i = 0; i < 4; ++i)
            af[i] = frag_read(sa, wm + i * 16 + l15, c8);
#pragma unroll
        for (int j = 0; j < 4; ++j)
            bf[j] = frag_read(sb, wn + j * 16 + l15, c8);
#pragma unroll
        for (int i = 0; i < 4; ++i)
#pragma unroll
            for (int j = 0; j < 4; ++j)
                acc[i][j] = __builtin_amdgcn_mfma_f32_16x16x32_bf16(af[i], bf[j], acc[i][j], 0, 0, 0);
    }
}

// ===========================================================================
// Fused-convert projection GEMM: A read DIRECTLY as f32 (reg-staged, T14
// issue-early/write-late split), W staged via global_load_lds (bf16).
//
// R6 lesson (VGPR_Count stayed 88): the pre-RA scheduler SANK the f32 A-loads
// down to their first use in writeA (minimizing live ranges), serializing
// load latency after the MFMA cluster. Fix: sched_barrier(0) fences pin the
// three regions {issue loads | MFMA | wait+cvt+ds_write} in source order
// (learn_hip rule #18: compiler reorders across inline waits/uses unless
// explicitly fenced). Expected tell: VGPR rises to ~120.
// ===========================================================================
struct Proj3 {
    const void* A[3];
    const void* W[3];
    const float* bias[3];
    __bf16* C[3];
    int vtmask;
};

__device__ inline void loadA32(const float* __restrict__ G, int tid, f32x4 (&v)[4][2])
{
    const int r  = tid >> 3;                          // 0..31
    const int co = ((tid & 7) ^ (r & 7)) * 8;         // swizzled source column
#pragma unroll
    for (int c = 0; c < 4; ++c) {
        const float* p = G + (long)(c * 32 + r) * HD + co;
        v[c][0] = *(const f32x4*)p;
        v[c][1] = *(const f32x4*)(p + 4);
    }
}

__device__ inline void writeA(__bf16* s, int tid, const f32x4 (&v)[4][2])
{
#pragma unroll
    for (int c = 0; c < 4; ++c) {
        bf16x8 r8;
#pragma unroll
        for (int i = 0; i < 4; ++i) {
            r8[i]     = (__bf16)v[c][0][i];
            r8[i + 4] = (__bf16)v[c][1][i];
        }
        *(bf16x8*)(s + c * 2048 + tid * 8) = r8;      // same layout as gld path
    }
}

__global__ __launch_bounds__(256) void gemm_projF(Proj3 p)
{
    __shared__ __bf16 sA[2][128 * 64];
    __shared__ __bf16 sB[2][128 * 64];

    const int tid = threadIdx.x;
    const int L = blockIdx.x;
    const int per = gridDim.x >> 3;
    const int wrk = (L & 7) * per + (L >> 3);
    const int n0 = (wrk & 7) * 128;
    const int m0 = ((wrk >> 3) & 63) * 128;
    const int z  = wrk >> 9;
    const bool vt = (p.vtmask >> z) & 1;

    const float*  Ag = (const float*)p.A[z] + (long)m0 * HD;
    const __bf16* Wg = (const __bf16*)p.W[z] + (long)n0 * HD;
    const float* bias = p.bias[z];
    __bf16* C = p.C[z];

    const int lane = tid & 63;
    const int l15  = lane & 15;
    const int quad = lane >> 4;
    const int wave = tid >> 6;
    const int wm = (wave >> 1) * 64;
    const int wn = (wave & 1) * 64;

    f32x4 acc[4][4];
    const f32x4 zero = {0.f, 0.f, 0.f, 0.f};
#pragma unroll
    for (int i = 0; i < 4; ++i)
#pragma unroll
        for (int j = 0; j < 4; ++j) acc[i][j] = zero;

    f32x4 av[4][2];
    // prologue: tile 0
    loadA32(Ag, tid, av);
    stage_tile(Wg, HD, sB[0], tid);
    writeA(sA[0], tid, av);              // vmcnt wait lands here (no MFMA yet)
    __syncthreads();

    int cur = 0;
    for (int kc = 0; kc < HD; kc += 64) {
        const int nxt = kc + 64;
        if (nxt < HD) {
            loadA32(Ag + nxt, tid, av);                  // issue A loads early
            stage_tile(Wg + nxt, HD, sB[cur ^ 1], tid);  // async W stage
        }
        __builtin_amdgcn_sched_barrier(0);   // loads may NOT sink below here
        mfma_ktile(sA[cur], sB[cur], wm, wn, l15, quad, acc);
        __builtin_amdgcn_sched_barrier(0);   // wait+cvt+write may NOT hoist up
        if (nxt < HD) writeA(sA[cur ^ 1], tid, av);      // cvt+ds_write late
        __syncthreads();
        cur ^= 1;
    }

#pragma unroll
    for (int j = 0; j < 4; ++j) {
        const int col = n0 + wn + j * 16 + l15;
        const float bv = bias[col];
#pragma unroll
        for (int i = 0; i < 4; ++i) {
#pragma unroll
            for (int r = 0; r < 4; ++r) {
                const int row = m0 + wm + i * 16 + quad * 4 + r;
                const float v = acc[i][j][r] + bv;
                if (vt) {
                    C[(((long)(row >> 11) * HD) + col) * SEQ + (row & (SEQ - 1))] = (__bf16)v;
                } else {
                    C[(long)row * HD + col] = (__bf16)v;
                }
            }
        }
    }
}

// ===========================================================================
// Legacy projection GEMM (R1 dbuf) — fallback path (f32/f32 reg-staged).
// ===========================================================================
template <typename TA, typename TW>
__global__ __launch_bounds__(256) void gemm_proj(Proj3 p)
{
    __shared__ __bf16 sA[2][128 * 64];
    __shared__ __bf16 sB[2][128 * 64];

    const int tid = threadIdx.x;
    const int L = blockIdx.x;
    const int per = gridDim.x >> 3;
    const int wrk = (L & 7) * per + (L >> 3);
    const int n0 = (wrk & 7) * 128;
    const int m0 = ((wrk >> 3) & 63) * 128;
    const int z  = wrk >> 9;
    const bool vt = (p.vtmask >> z) & 1;

    const TA* Ag = (const TA*)p.A[z] + (long)m0 * HD;
    const TW* Wg = (const TW*)p.W[z] + (long)n0 * HD;
    const float* bias = p.bias[z];
    __bf16* C = p.C[z];

    const int lane = tid & 63;
    const int l15  = lane & 15;
    const int quad = lane >> 4;
    const int wave = tid >> 6;
    const int wm = (wave >> 1) * 64;
    const int wn = (wave & 1) * 64;

    f32x4 acc[4][4];
    const f32x4 zero = {0.f, 0.f, 0.f, 0.f};
#pragma unroll
    for (int i = 0; i < 4; ++i)
#pragma unroll
        for (int j = 0; j < 4; ++j) acc[i][j] = zero;

    stage_tile(Ag, HD, sA[0], tid);
    stage_tile(Wg, HD, sB[0], tid);
    __syncthreads();

    int cur = 0;
    for (int kc = 0; kc < HD; kc += 64) {
        const int nxt = kc + 64;
        if (nxt < HD) {
            stage_tile(Ag + nxt, HD, sA[cur ^ 1], tid);
            stage_tile(Wg + nxt, HD, sB[cur ^ 1], tid);
        }
        mfma_ktile(sA[cur], sB[cur], wm, wn, l15, quad, acc);
        __syncthreads();
        cur ^= 1;
    }

#pragma unroll
    for (int j = 0; j < 4; ++j) {
        const int col = n0 + wn + j * 16 + l15;
        const float bv = bias[col];
#pragma unroll
        for (int i = 0; i < 4; ++i) {
#pragma unroll
            for (int r = 0; r < 4; ++r) {
                const int row = m0 + wm + i * 16 + quad * 4 + r;
                const float v = acc[i][j][r] + bv;
                if (vt) {
                    C[(((long)(row >> 11) * HD) + col) * SEQ + (row & (SEQ - 1))] = (__bf16)v;
                } else {
                    C[(long)row * HD + col] = (__bf16)v;
                }
            }
        }
    }
}

// ---------------------------------------------------------------------------
// Scores GEMM, [t][s] layout: Et[t][s] = exp(<q_t,k_s>*alpha) for s<=t, else 0.
// A=qp (rows t), B=kp (rows s). TRI blocks: m0 = tb*128 (t) >= n0 = sb*128 (s).
// Row-sums (softmax denominators, per t) accumulated via shfl-reduce + atomics.
// ---------------------------------------------------------------------------
template <typename OutT>
__global__ __launch_bounds__(256) void gemm_sc(
    const __bf16* __restrict__ A, const __bf16* __restrict__ B,
    OutT* __restrict__ C, float* __restrict__ gsum, float alpha)
{
    __shared__ __bf16 s1[2][128 * 64];
    __shared__ __bf16 s2[2][128 * 64];
    __shared__ float csum[128];

    const int tid = threadIdx.x;
    const int L = blockIdx.x;
    const int per = gridDim.x >> 3;
    const int wrk = (L & 7) * per + (L >> 3);
    const int Lt = wrk % 136;
    const int z  = wrk / 136;
    int tb = (int)((sqrtf(8.f * Lt + 1.f) - 1.f) * 0.5f);
    while ((tb + 1) * (tb + 2) / 2 <= Lt) ++tb;
    while (tb * (tb + 1) / 2 > Lt) --tb;
    const int sb = Lt - tb * (tb + 1) / 2;
    const int m0 = tb * 128;      // t (row), tb >= sb
    const int n0 = sb * 128;      // s (col)

    const __bf16* Ag = A + (long)z * SEQ * HD + (long)m0 * HD;
    const __bf16* Bg = B + (long)z * SEQ * HD + (long)n0 * HD;
    C += (long)z * SEQ * SEQ;
    gsum += (long)z * SEQ;
    if (tid < 128) csum[tid] = 0.f;    // visible after first __syncthreads

    const int lane = tid & 63, l15 = lane & 15, quad = lane >> 4;
    const int wave = tid >> 6;
    const int wm = (wave >> 1) * 64;
    const int wn = (wave & 1) * 64;

    f32x4 acc[4][4];
    const f32x4 zero = {0.f, 0.f, 0.f, 0.f};
#pragma unroll
    for (int i = 0; i < 4; ++i)
#pragma unroll
        for (int j = 0; j < 4; ++j) acc[i][j] = zero;

    stage_tile(Ag, HD, s1[0], tid);
    stage_tile(Bg, HD, s2[0], tid);
    __syncthreads();
    int cur = 0;
    for (int kc = 0; kc < HD; kc += 64) {
        const int nxt = kc + 64;
        if (nxt < HD) {
            stage_tile(Ag + nxt, HD, s1[cur ^ 1], tid);
            stage_tile(Bg + nxt, HD, s2[cur ^ 1], tid);
        }
        mfma_ktile(s1[cur], s2[cur], wm, wn, l15, quad, acc);
        __syncthreads();
        cur ^= 1;
    }

    float rsum[4][4];
#pragma unroll
    for (int i = 0; i < 4; ++i)
#pragma unroll
        for (int r = 0; r < 4; ++r) rsum[i][r] = 0.f;

#pragma unroll
    for (int j = 0; j < 4; ++j) {
        const int col = n0 + wn + j * 16 + l15;
#pragma unroll
        for (int i = 0; i < 4; ++i) {
#pragma unroll
            for (int r = 0; r < 4; ++r) {
                const int row = m0 + wm + i * 16 + quad * 4 + r;
                const float e = (col <= row) ? __expf(acc[i][j][r] * alpha) : 0.f;
                C[(long)row * SEQ + col] = (OutT)e;
                rsum[i][r] += e;
            }
        }
    }
#pragma unroll
    for (int i = 0; i < 4; ++i) {
#pragma unroll
        for (int r = 0; r < 4; ++r) {
            float v = rsum[i][r];
            v += __shfl_xor(v, 1); v += __shfl_xor(v, 2);
            v += __shfl_xor(v, 4); v += __shfl_xor(v, 8);
            if (l15 == 0) atomicAdd(&csum[wm + i * 16 + quad * 4 + r], v);
        }
    }
    __syncthreads();
    if (tid < 128) atomicAdd(&gsum[m0 + tid], csum[tid]);
}

// ---------------------------------------------------------------------------
// Context GEMM: C[t][h] = inv[t] * sum_{s<=t} Et[t][s] * vT[h][s].
// A=Et (lda=SEQ), B=vT (ldb=SEQ), causal K-limit Kend=m0+128, per-row scale
// from gsum in epilogue. m-block index goes through the pairing bijection
// 0,15,1,14,... so consecutively-dispatched blocks pair long+short K.
// ---------------------------------------------------------------------------
__global__ __launch_bounds__(256) void gemm_ctx(
    const __bf16* __restrict__ A, const __bf16* __restrict__ B,
    float* __restrict__ C, const float* __restrict__ gsum)
{
    __shared__ __bf16 s1[2][128 * 64];
    __shared__ __bf16 s2[2][128 * 64];
    __shared__ float rs[128];

    const int tid = threadIdx.x;
    const int L = blockIdx.x;
    const int per = gridDim.x >> 3;
    const int wrk = (L & 7) * per + (L >> 3);
    const int n0 = (wrk & 7) * 128;          // h
    const int q  = (wrk >> 3) & 15;
    const int mb = (q & 1) ? (15 - (q >> 1)) : (q >> 1);   // 0,15,1,14,...
    const int m0 = mb * 128;                 // t
    const int z  = wrk >> 7;

    const __bf16* Ag = A + (long)z * SEQ * SEQ + (long)m0 * SEQ;
    const __bf16* Bg = B + (long)z * HD * SEQ + (long)n0 * SEQ;
    C += (long)z * SEQ * HD;
    if (tid < 128) rs[tid] = gsum[(long)z * SEQ + m0 + tid];

    const int lane = tid & 63, l15 = lane & 15, quad = lane >> 4;
    const int wave = tid >> 6;
    const int wm = (wave >> 1) * 64;
    const int wn = (wave & 1) * 64;

    f32x4 acc[4][4];
    const f32x4 zero = {0.f, 0.f, 0.f, 0.f};
#pragma unroll
    for (int i = 0; i < 4; ++i)
#pragma unroll
        for (int j = 0; j < 4; ++j) acc[i][j] = zero;

    const int Kend = m0 + 128;

    stage_tile(Ag, SEQ, s1[0], tid);
    stage_tile(Bg, SEQ, s2[0], tid);
    __syncthreads();
    int cur = 0;
    for (int kc = 0; kc < Kend; kc += 64) {
        const int nxt = kc + 64;
        if (nxt < Kend) {
            stage_tile(Ag + nxt, SEQ, s1[cur ^ 1], tid);
            stage_tile(Bg + nxt, SEQ, s2[cur ^ 1], tid);
        }
        mfma_ktile(s1[cur], s2[cur], wm, wn, l15, quad, acc);
        __syncthreads();
        cur ^= 1;
    }

    float invr[4][4];
#pragma unroll
    for (int i = 0; i < 4; ++i)
#pragma unroll
        for (int r = 0; r < 4; ++r)
            invr[i][r] = 1.0f / rs[wm + i * 16 + quad * 4 + r];

#pragma unroll
    for (int j = 0; j < 4; ++j) {
        const int col = n0 + wn + j * 16 + l15;
#pragma unroll
        for (int i = 0; i < 4; ++i) {
#pragma unroll
            for (int r = 0; r < 4; ++r) {
                const int row = m0 + wm + i * 16 + quad * 4 + r;
                C[(long)row * HD + col] = acc[i][j][r] * invr[i][r];
            }
        }
    }
}

// ---------------------------------------------------------------------------
// Emit f32 attention output: Out[s][t] = Et[t][s] * inv[t]. 128x128 per block,
// 2x2 64x64 LDS-transposed subtiles; [64][68] padding; 64B-contiguous
// cluster stores.
// ---------------------------------------------------------------------------
__global__ __launch_bounds__(256) void emit_attn(
    const __bf16* __restrict__ Et, float* __restrict__ Out,
    const float* __restrict__ csum)
{
    __shared__ float tile[64][68];
    const int b = blockIdx.z;
    const int t0 = blockIdx.x * 128;
    const int s0 = blockIdx.y * 128;
    const __bf16* Eb = Et + (long)b * SEQ * SEQ;
    float* Ob = Out + (long)b * SEQ * SEQ;
    const int tid = threadIdx.x;

    if (s0 > t0 + 127) {     // fully masked: zero-fill f32 output
        const f32x4 z4 = {0.f, 0.f, 0.f, 0.f};
        const int c4 = (tid & 31) * 4;
        for (int r = tid >> 5; r < 128; r += 8)
            *(f32x4*)&Ob[(long)(s0 + r) * SEQ + t0 + c4] = z4;
        return;
    }

#pragma unroll
    for (int dt = 0; dt < 2; ++dt) {
#pragma unroll
        for (int dsb = 0; dsb < 2; ++dsb) {
            const int tt = t0 + dt * 64, ss = s0 + dsb * 64;
            const int c4 = (tid & 15) * 4;
#pragma unroll
            for (int r0 = 0; r0 < 64; r0 += 16) {
                const int tl = r0 + (tid >> 4);
                const float inv = 1.0f / csum[(long)b * SEQ + tt + tl];
                f32x4 e = load4f(&Eb[(long)(tt + tl) * SEQ + ss + c4]);
#pragma unroll
                for (int k = 0; k < 4; ++k) tile[tl][c4 + k] = e[k] * inv;
            }
            __syncthreads();
            const int sl = tid >> 2;            // 0..63 (s-local row)
            const int t4 = (tid & 3) * 4;       // cluster offset within 16-col group
#pragma unroll
            for (int qq = 0; qq < 4; ++qq) {
                f32x4 ov;
#pragma unroll
                for (int k = 0; k < 4; ++k) ov[k] = tile[qq * 16 + t4 + k][sl];
                *(f32x4*)&Ob[(long)(ss + sl) * SEQ + tt + qq * 16 + t4] = ov;
            }
            __syncthreads();
        }
    }
}

// ===========================================================================
// Legacy kernels (mid / fallback workspace paths) — unchanged semantics.
// ===========================================================================
template <bool TRI, bool CKLIM, bool EXPSUM, typename OutT>
__global__ __launch_bounds__(256) void gemm_bt(
    const __bf16* __restrict__ A, long strideA, int lda,
    const __bf16* __restrict__ B, long strideB, int ldb,
    OutT* __restrict__ C, long strideC, int ldc,
    float* __restrict__ gsum,
    int K, float alpha)
{
    __shared__ __bf16 sA[2][128 * 64];
    __shared__ __bf16 sB[2][128 * 64];
    __shared__ float csum[128];

    const int tid = threadIdx.x;
    const int L = blockIdx.x;
    const int per = gridDim.x >> 3;
    const int wrk = (L & 7) * per + (L >> 3);
    int n0, m0, z;
    if (TRI) {
        const int Lt = wrk % 136;
        z = wrk / 136;
        int tb = (int)((sqrtf(8.f * Lt + 1.f) - 1.f) * 0.5f);
        while ((tb + 1) * (tb + 2) / 2 <= Lt) ++tb;
        while (tb * (tb + 1) / 2 > Lt) --tb;
        const int sb = Lt - tb * (tb + 1) / 2;
        n0 = tb * 128;
        m0 = sb * 128;
    } else {
        n0 = (wrk & 7) * 128;
        m0 = ((wrk >> 3) & 15) * 128;
        z  = wrk >> 7;
    }

    const __bf16* Ag = A + (long)z * strideA + (long)m0 * lda;
    const __bf16* Bg = B + (long)z * strideB + (long)n0 * ldb;
    C += (long)z * strideC;
    if (EXPSUM) {
        gsum += (long)z * SEQ;
        if (tid < 128) csum[tid] = 0.f;
    }

    const int lane = tid & 63;
    const int l15  = lane & 15;
    const int quad = lane >> 4;
    const int wave = tid >> 6;
    const int wm = (wave >> 1) * 64;
    const int wn = (wave & 1) * 64;

    f32x4 acc[4][4];
    const f32x4 zero = {0.f, 0.f, 0.f, 0.f};
#pragma unroll
    for (int i = 0; i < 4; ++i)
#pragma unroll
        for (int j = 0; j < 4; ++j) acc[i][j] = zero;

    const int Kend = CKLIM ? min(K, m0 + 128) : K;

    stage_tile(Ag, lda, sA[0], tid);
    stage_tile(Bg, ldb, sB[0], tid);
    __syncthreads();

    int cur = 0;
    for (int kc = 0; kc < Kend; kc += 64) {
        const int nxt = kc + 64;
        if (nxt < Kend) {
            stage_tile(Ag + nxt, lda, sA[cur ^ 1], tid);
            stage_tile(Bg + nxt, ldb, sB[cur ^ 1], tid);
        }
        mfma_ktile(sA[cur], sB[cur], wm, wn, l15, quad, acc);
        __syncthreads();
        cur ^= 1;
    }

#pragma unroll
    for (int j = 0; j < 4; ++j) {
        const int col = n0 + wn + j * 16 + l15;
        float part = 0.f;
#pragma unroll
        for (int i = 0; i < 4; ++i) {
#pragma unroll
            for (int r = 0; r < 4; ++r) {
                const int row = m0 + wm + i * 16 + quad * 4 + r;
                float v = acc[i][j][r] * alpha;
                if (EXPSUM) {
                    v = __expf(v);
                    if (row <= col) part += v;
                }
                C[(long)row * ldc + col] = (OutT)v;
            }
        }
        if (EXPSUM) atomicAdd(&csum[wn + j * 16 + l15], part);
    }
    if (EXPSUM) {
        __syncthreads();
        if (tid < 128) atomicAdd(&gsum[n0 + tid], csum[tid]);
    }
}

template <typename ET>
__global__ __launch_bounds__(256) void scale_emit(
    const ET* __restrict__ E, float* __restrict__ Out,
    const float* __restrict__ csum, __bf16* __restrict__ AT)
{
    __shared__ __bf16 tile[64][65];
    const int b = blockIdx.z;
    const int t0 = blockIdx.x * 128;
    const int s0 = blockIdx.y * 128;
    const ET* Eb = E + (long)b * SEQ * SEQ;
    float* Ob = Out + (long)b * SEQ * SEQ;
    __bf16* Ab = AT + (long)b * SEQ * SEQ;
    const int tid = threadIdx.x;

    if (s0 > t0 + 127) {
        const f32x4 z4 = {0.f, 0.f, 0.f, 0.f};
        const int c4 = (tid & 31) * 4;
        for (int r = tid >> 5; r < 128; r += 8)
            *(f32x4*)&Ob[(long)(s0 + r) * SEQ + t0 + c4] = z4;
        return;
    }

#pragma unroll
    for (int ds = 0; ds < 2; ++ds) {
#pragma unroll
        for (int dt = 0; dt < 2; ++dt) {
            const int ss = s0 + ds * 64, tt = t0 + dt * 64;
            const int c4 = (tid & 15) * 4;
            const int tcol = tt + c4;
            const f32x4 sv = *(const f32x4*)&csum[(long)b * SEQ + tcol];
            f32x4 inv;
#pragma unroll
            for (int k = 0; k < 4; ++k) inv[k] = 1.0f / sv[k];
#pragma unroll
            for (int r0 = 0; r0 < 64; r0 += 16) {
                const int s = ss + r0 + (tid >> 4);
                f32x4 e = load4f(&Eb[(long)s * SEQ + tcol]);
                f32x4 p;
#pragma unroll
                for (int k = 0; k < 4; ++k)
                    p[k] = (s <= tcol + k) ? e[k] * inv[k] : 0.f;
                *(f32x4*)&Ob[(long)s * SEQ + tcol] = p;
#pragma unroll
                for (int k = 0; k < 4; ++k)
                    tile[r0 + (tid >> 4)][c4 + k] = (__bf16)p[k];
            }
            __syncthreads();
            const int tr = tid >> 2;
            const int sc = (tid & 3) * 16;
            __bf16 v[16];
#pragma unroll
            for (int jj = 0; jj < 16; ++jj) v[jj] = tile[sc + jj][tr];
            *(bf16x8*)&Ab[(long)(tt + tr) * SEQ + ss + sc]     = *(bf16x8*)v;
            *(bf16x8*)&Ab[(long)(tt + tr) * SEQ + ss + sc + 8] = *(bf16x8*)(v + 8);
            __syncthreads();
        }
    }
}

// ---------------------------------------------------------------------------
// Batched f32 -> bf16 convert: up to 6 jobs in one dispatch.
// ---------------------------------------------------------------------------
struct CvtJob { const float* in; __bf16* out; int nblk; };
struct Cvt6 { CvtJob j[6]; };
__global__ __launch_bounds__(256) void cvt_bf16(Cvt6 c)
{
    const CvtJob jb = c.j[blockIdx.y];
    if ((int)blockIdx.x >= jb.nblk) return;
    const long i = ((long)blockIdx.x * 256 + threadIdx.x) * 8;
    *(bf16x8*)&jb.out[i] = load8cvt(&jb.in[i]);
}

// ---------------------------------------------------------------------------
extern "C" void kernel_launch(void* const* d_in, const int* in_sizes, int n_in,
                              void* d_out, int out_size, void* d_ws, size_t ws_size,
                              hipStream_t stream)
{
    const float* queries = (const float*)d_in[0];
    const float* keys    = (const float*)d_in[1];
    const float* values  = (const float*)d_in[2];
    const float* Wq = (const float*)d_in[3];
    const float* bq = (const float*)d_in[4];
    const float* Wk = (const float*)d_in[5];
    const float* bk = (const float*)d_in[6];
    const float* Wv = (const float*)d_in[7];
    const float* bv = (const float*)d_in[8];

    const long tokens = (long)NB * SEQ;           // 8192
    const long pe = tokens * HD;                  // elems per 16 MiB buffer
    const size_t SLOT = (size_t)pe * sizeof(__bf16);   // 16 MiB
    const int WBLK = WEL / 2048;                  // 512 cvt blocks per weight

    float* outCtx  = (float*)d_out;               // [4][2048][1024] f32
    float* outAttn = outCtx + tokens * HD;        // [4][2048][2048] f32
    __bf16* wb = (__bf16*)outAttn;                // bf16 weights: dead-at-start
    __bf16* Wqb = wb, *Wkb = wb + WEL, *Wvb = wb + 2 * WEL;

    const dim3 blk(256);
    char* w = (char*)d_ws;
    __bf16 *qp, *kp, *vT;

    // weights-only convert (12MB read / 6MB write)
    Cvt6 cvw = {{{Wq, Wqb, WBLK}, {Wk, Wkb, WBLK}, {Wv, Wvb, WBLK},
                 {nullptr, nullptr, 0}, {nullptr, nullptr, 0}, {nullptr, nullptr, 0}}};

    if (ws_size >= 6 * SLOT) {
        // [Et0][Et1][colsum...][qp][kp][vT]; proj reads f32 activations direct.
        qp = (__bf16*)(w + 3 * SLOT);
        kp = (__bf16*)(w + 4 * SLOT);
        vT = (__bf16*)(w + 5 * SLOT);
        __bf16* Ebf = (__bf16*)w;                 // slots 0-1
        float* colsum = (float*)(w + 2 * SLOT);   // slot 2

        hipMemsetAsync(colsum, 0, (size_t)NB * SEQ * sizeof(float), stream);
        cvt_bf16<<<dim3(WBLK, 3), blk, 0, stream>>>(cvw);
        Proj3 pj = {{queries, keys, values}, {Wqb, Wkb, Wvb}, {bq, bk, bv},
                    {qp, kp, vT}, 4};
        gemm_projF<<<dim3(512 * 3), blk, 0, stream>>>(pj);

        // Et[b][t][s] = exp(<q_t,k_s>/32) masked; rowsums into colsum
        gemm_sc<__bf16><<<dim3(544), blk, 0, stream>>>(qp, kp, Ebf, colsum, 0.03125f);
        // f32 attn output (transposed, normalized)
        emit_attn<<<dim3(SEQ / 128, SEQ / 128, NB), blk, 0, stream>>>(
            Ebf, outAttn, colsum);
        // context with per-row normalization in epilogue
        gemm_ctx<<<dim3(512), blk, 0, stream>>>(Ebf, vT, outCtx, colsum);
    } else if (ws_size >= 4 * SLOT) {
        // [qp][kp][vT][unused]; attnT aliases qp+kp (dead after scores);
        // E stays f32 in outAttn (in-place scale_emit). Legacy downstream.
        float* colsum = outCtx;
        hipMemsetAsync(colsum, 0, (size_t)NB * SEQ * sizeof(float), stream);
        qp = (__bf16*)w;
        kp = (__bf16*)(w + SLOT);
        vT = (__bf16*)(w + 2 * SLOT);
        __bf16* attnT = (__bf16*)d_ws;            // slots 0-1 after scores

        cvt_bf16<<<dim3(WBLK, 3), blk, 0, stream>>>(cvw);
        Proj3 pj = {{queries, keys, values}, {Wqb, Wkb, Wvb}, {bq, bk, bv},
                    {qp, kp, vT}, 4};
        gemm_projF<<<dim3(512 * 3), blk, 0, stream>>>(pj);

        gemm_bt<true, false, true, float><<<dim3(544), blk, 0, stream>>>(
            kp, (long)SEQ * HD, HD, qp, (long)SEQ * HD, HD,
            outAttn, (long)SEQ * SEQ, SEQ, colsum, HD, 0.03125f);
        scale_emit<float><<<dim3(SEQ / 128, SEQ / 128, NB), blk, 0, stream>>>(
            outAttn, outAttn, colsum, attnT);
        gemm_bt<false, true, false, float><<<dim3(512), blk, 0, stream>>>(
            attnT, (long)SEQ * SEQ, SEQ, vT, (long)HD * SEQ, SEQ,
            outCtx, (long)SEQ * HD, HD, nullptr, SEQ, 1.0f);
    } else {
        // fallback: f32-staged operands straight from inputs; [qp][kp][vT]
        float* colsum = outCtx;
        hipMemsetAsync(colsum, 0, (size_t)NB * SEQ * sizeof(float), stream);
        qp = (__bf16*)w;
        kp = (__bf16*)(w + SLOT);
        vT = (__bf16*)(w + 2 * SLOT);
        __bf16* attnT = (__bf16*)d_ws;
        Proj3 pj = {{queries, keys, values}, {Wq, Wk, Wv}, {bq, bk, bv},
                    {qp, kp, vT}, 4};
        gemm_proj<float, float><<<dim3(512 * 3), blk, 0, stream>>>(pj);

        gemm_bt<true, false, true, float><<<dim3(544), blk, 0, stream>>>(
            kp, (long)SEQ * HD, HD, qp, (long)SEQ * HD, HD,
            outAttn, (long)SEQ * SEQ, SEQ, colsum, HD, 0.03125f);
        scale_emit<float><<<dim3(SEQ / 128, SEQ / 128, NB), blk, 0, stream>>>(
            outAttn, outAttn, colsum, attnT);
        gemm_bt<false, true, false, float><<<dim3(512), blk, 0, stream>>>(
            attnT, (long)SEQ * SEQ, SEQ, vT, (long)HD * SEQ, SEQ,
            outCtx, (long)SEQ * HD, HD, nullptr, SEQ, 1.0f);
    }
}

// Round 8
// 380.148 us; speedup vs baseline: 1.0089x; 1.0089x over previous
//
#include <hip/hip_runtime.h>
#include <math.h>

typedef __bf16 bf16x8 __attribute__((ext_vector_type(8)));
typedef __bf16 bf16x4 __attribute__((ext_vector_type(4)));
typedef float f32x4 __attribute__((ext_vector_type(4)));

#define HD 1024
#define SEQ 2048
#define NB 4
#define WEL (HD * HD)   // elements per weight matrix

// Load 8 contiguous elements as bf16x8, converting f32 -> bf16 if needed.
__device__ inline bf16x8 load8cvt(const __bf16* p) { return *(const bf16x8*)p; }
__device__ inline bf16x8 load8cvt(const float* p) {
    f32x4 a = *(const f32x4*)p;
    f32x4 b = *(const f32x4*)(p + 4);
    bf16x8 r;
#pragma unroll
    for (int i = 0; i < 4; ++i) { r[i] = (__bf16)a[i]; r[i + 4] = (__bf16)b[i]; }
    return r;
}

// Load 4 contiguous elements as f32x4 (from f32 or bf16 source).
__device__ inline f32x4 load4f(const float* p) { return *(const f32x4*)p; }
__device__ inline f32x4 load4f(const __bf16* p) {
    bf16x4 v = *(const bf16x4*)p;
    f32x4 r;
#pragma unroll
    for (int i = 0; i < 4; ++i) r[i] = (float)v[i];
    return r;
}

// Async global->LDS, 16 bytes per lane (global_load_lds_dwordx4).
__device__ inline void gld_lds16(const void* g, void* l) {
    __builtin_amdgcn_global_load_lds(
        (const __attribute__((address_space(1))) unsigned int*)g,
        (__attribute__((address_space(3))) unsigned int*)l, 16, 0, 0);
}

// ===========================================================================
// 128x128 BK=64 tile machinery (shared by all GEMMs). XOR-swizzled LDS tile:
// LDS chunk (row, j) holds GLOBAL chunk (row, j ^ (row&7)); global source is
// pre-swizzled so the LDS destination stays linear (global_load_lds rule).
// ===========================================================================
template <typename T>
__device__ inline void stage_tile(const T* __restrict__ G, int ld, __bf16* s, int tid)
{
    const int r  = tid >> 3;                          // 0..31
    const int co = ((tid & 7) ^ (r & 7)) * 8;         // swizzled source column
    if constexpr (sizeof(T) == 2) {
        __bf16* dst = s + (tid >> 6) * 512;           // wave-uniform base
#pragma unroll
        for (int c = 0; c < 4; ++c)
            gld_lds16(G + (long)(c * 32 + r) * ld + co, dst + c * 2048);
    } else {
#pragma unroll
        for (int c = 0; c < 4; ++c)
            *(bf16x8*)(s + c * 2048 + tid * 8) = load8cvt(G + (long)(c * 32 + r) * ld + co);
    }
}

__device__ inline bf16x8 frag_read(const __bf16* s, int row, int c)
{
    return *(const bf16x8*)&s[row * 64 + ((c ^ (row & 7)) * 8)];
}

__device__ inline void mfma_ktile(const __bf16* __restrict__ sa,
                                  const __bf16* __restrict__ sb,
                                  int wm, int wn, int l15, int quad,
                                  f32x4 (&acc)[4][4])
{
#pragma unroll
    for (int kk = 0; kk < 64; kk += 32) {
        const int c8 = quad + (kk >> 3);
        bf16x8 af[4], bf[4];
#pragma unroll
        for (int i = 0; i < 4; ++i)
            af[i] = frag_read(sa, wm + i * 16 + l15, c8);
#pragma unroll
        for (int j = 0; j < 4; ++j)
            bf[j] = frag_read(sb, wn + j * 16 + l15, c8);
#pragma unroll
        for (int i = 0; i < 4; ++i)
#pragma unroll
            for (int j = 0; j < 4; ++j)
                acc[i][j] = __builtin_amdgcn_mfma_f32_16x16x32_bf16(af[i], bf[j], acc[i][j], 0, 0, 0);
    }
}

// ===========================================================================
// Fused-convert projection GEMM: A read DIRECTLY as f32 (reg-staged, T14
// issue-early/write-late split), W staged via global_load_lds (bf16).
//
// R6/R7 lesson (VGPR stayed 88 both rounds): the A-loads lived in their own
// `if (nxt < HD)` basic block, and LLVM's MachineSink pass (cross-BB, runs
// BEFORE the scheduler that honors sched_barrier) sank them into the writeA
// block where they're first used. Intra-BB fences cannot stop a cross-BB
// sink. Fix: peel the loop so the body is STRAIGHT-LINE (loads unconditional,
// 15 iterations staging tiles 1..15; last tile computed after the loop).
// With everything in one BB, MachineSink has nowhere to sink and the fence
// pair pins {issue loads | MFMA | vmcnt-wait + cvt + ds_write}.
// Expected tell: VGPR ~120 (av[4][2] live across the MFMA cluster).
// ===========================================================================
struct Proj3 {
    const void* A[3];
    const void* W[3];
    const float* bias[3];
    __bf16* C[3];
    int vtmask;
};

__device__ inline void loadA32(const float* __restrict__ G, int tid, f32x4 (&v)[4][2])
{
    const int r  = tid >> 3;                          // 0..31
    const int co = ((tid & 7) ^ (r & 7)) * 8;         // swizzled source column
#pragma unroll
    for (int c = 0; c < 4; ++c) {
        const float* p = G + (long)(c * 32 + r) * HD + co;
        v[c][0] = *(const f32x4*)p;
        v[c][1] = *(const f32x4*)(p + 4);
    }
}

__device__ inline void writeA(__bf16* s, int tid, const f32x4 (&v)[4][2])
{
#pragma unroll
    for (int c = 0; c < 4; ++c) {
        bf16x8 r8;
#pragma unroll
        for (int i = 0; i < 4; ++i) {
            r8[i]     = (__bf16)v[c][0][i];
            r8[i + 4] = (__bf16)v[c][1][i];
        }
        *(bf16x8*)(s + c * 2048 + tid * 8) = r8;      // same layout as gld path
    }
}

__global__ __launch_bounds__(256) void gemm_projF(Proj3 p)
{
    __shared__ __bf16 sA[2][128 * 64];
    __shared__ __bf16 sB[2][128 * 64];

    const int tid = threadIdx.x;
    const int L = blockIdx.x;
    const int per = gridDim.x >> 3;
    const int wrk = (L & 7) * per + (L >> 3);
    const int n0 = (wrk & 7) * 128;
    const int m0 = ((wrk >> 3) & 63) * 128;
    const int z  = wrk >> 9;
    const bool vt = (p.vtmask >> z) & 1;

    const float*  Ag = (const float*)p.A[z] + (long)m0 * HD;
    const __bf16* Wg = (const __bf16*)p.W[z] + (long)n0 * HD;
    const float* bias = p.bias[z];
    __bf16* C = p.C[z];

    const int lane = tid & 63;
    const int l15  = lane & 15;
    const int quad = lane >> 4;
    const int wave = tid >> 6;
    const int wm = (wave >> 1) * 64;
    const int wn = (wave & 1) * 64;

    f32x4 acc[4][4];
    const f32x4 zero = {0.f, 0.f, 0.f, 0.f};
#pragma unroll
    for (int i = 0; i < 4; ++i)
#pragma unroll
        for (int j = 0; j < 4; ++j) acc[i][j] = zero;

    f32x4 av[4][2];
    // prologue: tile 0 staged (A via regs, W via global_load_lds)
    loadA32(Ag, tid, av);
    stage_tile(Wg, HD, sB[0], tid);
    writeA(sA[0], tid, av);              // vmcnt wait lands here (no MFMA yet)
    __syncthreads();

    // Straight-line steady-state: 15 iterations, loads UNCONDITIONAL (same BB
    // as MFMA + writeA, so MachineSink cannot move them; fences bind).
    int cur = 0;
    for (int kc = 0; kc + 64 < HD; kc += 64) {
        const int nxt = kc + 64;
        loadA32(Ag + nxt, tid, av);                  // issue A loads early
        stage_tile(Wg + nxt, HD, sB[cur ^ 1], tid);  // async W stage
        __builtin_amdgcn_sched_barrier(0);   // loads may NOT move below here
        mfma_ktile(sA[cur], sB[cur], wm, wn, l15, quad, acc);
        __builtin_amdgcn_sched_barrier(0);   // wait+cvt+write may NOT hoist up
        writeA(sA[cur ^ 1], tid, av);        // cvt+ds_write late (waits A only)
        __syncthreads();
        cur ^= 1;
    }
    // epilogue tile (already staged by last iteration)
    mfma_ktile(sA[cur], sB[cur], wm, wn, l15, quad, acc);

#pragma unroll
    for (int j = 0; j < 4; ++j) {
        const int col = n0 + wn + j * 16 + l15;
        const float bv = bias[col];
#pragma unroll
        for (int i = 0; i < 4; ++i) {
#pragma unroll
            for (int r = 0; r < 4; ++r) {
                const int row = m0 + wm + i * 16 + quad * 4 + r;
                const float v = acc[i][j][r] + bv;
                if (vt) {
                    C[(((long)(row >> 11) * HD) + col) * SEQ + (row & (SEQ - 1))] = (__bf16)v;
                } else {
                    C[(long)row * HD + col] = (__bf16)v;
                }
            }
        }
    }
}

// ===========================================================================
// Legacy projection GEMM (R1 dbuf) — fallback path (f32/f32 reg-staged).
// ===========================================================================
template <typename TA, typename TW>
__global__ __launch_bounds__(256) void gemm_proj(Proj3 p)
{
    __shared__ __bf16 sA[2][128 * 64];
    __shared__ __bf16 sB[2][128 * 64];

    const int tid = threadIdx.x;
    const int L = blockIdx.x;
    const int per = gridDim.x >> 3;
    const int wrk = (L & 7) * per + (L >> 3);
    const int n0 = (wrk & 7) * 128;
    const int m0 = ((wrk >> 3) & 63) * 128;
    const int z  = wrk >> 9;
    const bool vt = (p.vtmask >> z) & 1;

    const TA* Ag = (const TA*)p.A[z] + (long)m0 * HD;
    const TW* Wg = (const TW*)p.W[z] + (long)n0 * HD;
    const float* bias = p.bias[z];
    __bf16* C = p.C[z];

    const int lane = tid & 63;
    const int l15  = lane & 15;
    const int quad = lane >> 4;
    const int wave = tid >> 6;
    const int wm = (wave >> 1) * 64;
    const int wn = (wave & 1) * 64;

    f32x4 acc[4][4];
    const f32x4 zero = {0.f, 0.f, 0.f, 0.f};
#pragma unroll
    for (int i = 0; i < 4; ++i)
#pragma unroll
        for (int j = 0; j < 4; ++j) acc[i][j] = zero;

    stage_tile(Ag, HD, sA[0], tid);
    stage_tile(Wg, HD, sB[0], tid);
    __syncthreads();

    int cur = 0;
    for (int kc = 0; kc < HD; kc += 64) {
        const int nxt = kc + 64;
        if (nxt < HD) {
            stage_tile(Ag + nxt, HD, sA[cur ^ 1], tid);
            stage_tile(Wg + nxt, HD, sB[cur ^ 1], tid);
        }
        mfma_ktile(sA[cur], sB[cur], wm, wn, l15, quad, acc);
        __syncthreads();
        cur ^= 1;
    }

#pragma unroll
    for (int j = 0; j < 4; ++j) {
        const int col = n0 + wn + j * 16 + l15;
        const float bv = bias[col];
#pragma unroll
        for (int i = 0; i < 4; ++i) {
#pragma unroll
            for (int r = 0; r < 4; ++r) {
                const int row = m0 + wm + i * 16 + quad * 4 + r;
                const float v = acc[i][j][r] + bv;
                if (vt) {
                    C[(((long)(row >> 11) * HD) + col) * SEQ + (row & (SEQ - 1))] = (__bf16)v;
                } else {
                    C[(long)row * HD + col] = (__bf16)v;
                }
            }
        }
    }
}

// ---------------------------------------------------------------------------
// Scores GEMM, [t][s] layout: Et[t][s] = exp(<q_t,k_s>*alpha) for s<=t, else 0.
// A=qp (rows t), B=kp (rows s). TRI blocks: m0 = tb*128 (t) >= n0 = sb*128 (s).
// Row-sums (softmax denominators, per t) accumulated via shfl-reduce + atomics.
// ---------------------------------------------------------------------------
template <typename OutT>
__global__ __launch_bounds__(256) void gemm_sc(
    const __bf16* __restrict__ A, const __bf16* __restrict__ B,
    OutT* __restrict__ C, float* __restrict__ gsum, float alpha)
{
    __shared__ __bf16 s1[2][128 * 64];
    __shared__ __bf16 s2[2][128 * 64];
    __shared__ float csum[128];

    const int tid = threadIdx.x;
    const int L = blockIdx.x;
    const int per = gridDim.x >> 3;
    const int wrk = (L & 7) * per + (L >> 3);
    const int Lt = wrk % 136;
    const int z  = wrk / 136;
    int tb = (int)((sqrtf(8.f * Lt + 1.f) - 1.f) * 0.5f);
    while ((tb + 1) * (tb + 2) / 2 <= Lt) ++tb;
    while (tb * (tb + 1) / 2 > Lt) --tb;
    const int sb = Lt - tb * (tb + 1) / 2;
    const int m0 = tb * 128;      // t (row), tb >= sb
    const int n0 = sb * 128;      // s (col)

    const __bf16* Ag = A + (long)z * SEQ * HD + (long)m0 * HD;
    const __bf16* Bg = B + (long)z * SEQ * HD + (long)n0 * HD;
    C += (long)z * SEQ * SEQ;
    gsum += (long)z * SEQ;
    if (tid < 128) csum[tid] = 0.f;    // visible after first __syncthreads

    const int lane = tid & 63, l15 = lane & 15, quad = lane >> 4;
    const int wave = tid >> 6;
    const int wm = (wave >> 1) * 64;
    const int wn = (wave & 1) * 64;

    f32x4 acc[4][4];
    const f32x4 zero = {0.f, 0.f, 0.f, 0.f};
#pragma unroll
    for (int i = 0; i < 4; ++i)
#pragma unroll
        for (int j = 0; j < 4; ++j) acc[i][j] = zero;

    stage_tile(Ag, HD, s1[0], tid);
    stage_tile(Bg, HD, s2[0], tid);
    __syncthreads();
    int cur = 0;
    for (int kc = 0; kc < HD; kc += 64) {
        const int nxt = kc + 64;
        if (nxt < HD) {
            stage_tile(Ag + nxt, HD, s1[cur ^ 1], tid);
            stage_tile(Bg + nxt, HD, s2[cur ^ 1], tid);
        }
        mfma_ktile(s1[cur], s2[cur], wm, wn, l15, quad, acc);
        __syncthreads();
        cur ^= 1;
    }

    float rsum[4][4];
#pragma unroll
    for (int i = 0; i < 4; ++i)
#pragma unroll
        for (int r = 0; r < 4; ++r) rsum[i][r] = 0.f;

#pragma unroll
    for (int j = 0; j < 4; ++j) {
        const int col = n0 + wn + j * 16 + l15;
#pragma unroll
        for (int i = 0; i < 4; ++i) {
#pragma unroll
            for (int r = 0; r < 4; ++r) {
                const int row = m0 + wm + i * 16 + quad * 4 + r;
                const float e = (col <= row) ? __expf(acc[i][j][r] * alpha) : 0.f;
                C[(long)row * SEQ + col] = (OutT)e;
                rsum[i][r] += e;
            }
        }
    }
#pragma unroll
    for (int i = 0; i < 4; ++i) {
#pragma unroll
        for (int r = 0; r < 4; ++r) {
            float v = rsum[i][r];
            v += __shfl_xor(v, 1); v += __shfl_xor(v, 2);
            v += __shfl_xor(v, 4); v += __shfl_xor(v, 8);
            if (l15 == 0) atomicAdd(&csum[wm + i * 16 + quad * 4 + r], v);
        }
    }
    __syncthreads();
    if (tid < 128) atomicAdd(&gsum[m0 + tid], csum[tid]);
}

// ---------------------------------------------------------------------------
// Context GEMM: C[t][h] = inv[t] * sum_{s<=t} Et[t][s] * vT[h][s].
// A=Et (lda=SEQ), B=vT (ldb=SEQ), causal K-limit Kend=m0+128, per-row scale
// from gsum in epilogue. m-block index goes through the pairing bijection
// 0,15,1,14,... so consecutively-dispatched blocks pair long+short K.
// ---------------------------------------------------------------------------
__global__ __launch_bounds__(256) void gemm_ctx(
    const __bf16* __restrict__ A, const __bf16* __restrict__ B,
    float* __restrict__ C, const float* __restrict__ gsum)
{
    __shared__ __bf16 s1[2][128 * 64];
    __shared__ __bf16 s2[2][128 * 64];
    __shared__ float rs[128];

    const int tid = threadIdx.x;
    const int L = blockIdx.x;
    const int per = gridDim.x >> 3;
    const int wrk = (L & 7) * per + (L >> 3);
    const int n0 = (wrk & 7) * 128;          // h
    const int q  = (wrk >> 3) & 15;
    const int mb = (q & 1) ? (15 - (q >> 1)) : (q >> 1);   // 0,15,1,14,...
    const int m0 = mb * 128;                 // t
    const int z  = wrk >> 7;

    const __bf16* Ag = A + (long)z * SEQ * SEQ + (long)m0 * SEQ;
    const __bf16* Bg = B + (long)z * HD * SEQ + (long)n0 * SEQ;
    C += (long)z * SEQ * HD;
    if (tid < 128) rs[tid] = gsum[(long)z * SEQ + m0 + tid];

    const int lane = tid & 63, l15 = lane & 15, quad = lane >> 4;
    const int wave = tid >> 6;
    const int wm = (wave >> 1) * 64;
    const int wn = (wave & 1) * 64;

    f32x4 acc[4][4];
    const f32x4 zero = {0.f, 0.f, 0.f, 0.f};
#pragma unroll
    for (int i = 0; i < 4; ++i)
#pragma unroll
        for (int j = 0; j < 4; ++j) acc[i][j] = zero;

    const int Kend = m0 + 128;

    stage_tile(Ag, SEQ, s1[0], tid);
    stage_tile(Bg, SEQ, s2[0], tid);
    __syncthreads();
    int cur = 0;
    for (int kc = 0; kc < Kend; kc += 64) {
        const int nxt = kc + 64;
        if (nxt < Kend) {
            stage_tile(Ag + nxt, SEQ, s1[cur ^ 1], tid);
            stage_tile(Bg + nxt, SEQ, s2[cur ^ 1], tid);
        }
        mfma_ktile(s1[cur], s2[cur], wm, wn, l15, quad, acc);
        __syncthreads();
        cur ^= 1;
    }

    float invr[4][4];
#pragma unroll
    for (int i = 0; i < 4; ++i)
#pragma unroll
        for (int r = 0; r < 4; ++r)
            invr[i][r] = 1.0f / rs[wm + i * 16 + quad * 4 + r];

#pragma unroll
    for (int j = 0; j < 4; ++j) {
        const int col = n0 + wn + j * 16 + l15;
#pragma unroll
        for (int i = 0; i < 4; ++i) {
#pragma unroll
            for (int r = 0; r < 4; ++r) {
                const int row = m0 + wm + i * 16 + quad * 4 + r;
                C[(long)row * HD + col] = acc[i][j][r] * invr[i][r];
            }
        }
    }
}

// ---------------------------------------------------------------------------
// Emit f32 attention output: Out[s][t] = Et[t][s] * inv[t]. 128x128 per block,
// 2x2 64x64 LDS-transposed subtiles; [64][68] padding; 64B-contiguous
// cluster stores.
// ---------------------------------------------------------------------------
__global__ __launch_bounds__(256) void emit_attn(
    const __bf16* __restrict__ Et, float* __restrict__ Out,
    const float* __restrict__ csum)
{
    __shared__ float tile[64][68];
    const int b = blockIdx.z;
    const int t0 = blockIdx.x * 128;
    const int s0 = blockIdx.y * 128;
    const __bf16* Eb = Et + (long)b * SEQ * SEQ;
    float* Ob = Out + (long)b * SEQ * SEQ;
    const int tid = threadIdx.x;

    if (s0 > t0 + 127) {     // fully masked: zero-fill f32 output
        const f32x4 z4 = {0.f, 0.f, 0.f, 0.f};
        const int c4 = (tid & 31) * 4;
        for (int r = tid >> 5; r < 128; r += 8)
            *(f32x4*)&Ob[(long)(s0 + r) * SEQ + t0 + c4] = z4;
        return;
    }

#pragma unroll
    for (int dt = 0; dt < 2; ++dt) {
#pragma unroll
        for (int dsb = 0; dsb < 2; ++dsb) {
            const int tt = t0 + dt * 64, ss = s0 + dsb * 64;
            const int c4 = (tid & 15) * 4;
#pragma unroll
            for (int r0 = 0; r0 < 64; r0 += 16) {
                const int tl = r0 + (tid >> 4);
                const float inv = 1.0f / csum[(long)b * SEQ + tt + tl];
                f32x4 e = load4f(&Eb[(long)(tt + tl) * SEQ + ss + c4]);
#pragma unroll
                for (int k = 0; k < 4; ++k) tile[tl][c4 + k] = e[k] * inv;
            }
            __syncthreads();
            const int sl = tid >> 2;            // 0..63 (s-local row)
            const int t4 = (tid & 3) * 4;       // cluster offset within 16-col group
#pragma unroll
            for (int qq = 0; qq < 4; ++qq) {
                f32x4 ov;
#pragma unroll
                for (int k = 0; k < 4; ++k) ov[k] = tile[qq * 16 + t4 + k][sl];
                *(f32x4*)&Ob[(long)(ss + sl) * SEQ + tt + qq * 16 + t4] = ov;
            }
            __syncthreads();
        }
    }
}

// ===========================================================================
// Legacy kernels (mid / fallback workspace paths) — unchanged semantics.
// ===========================================================================
template <bool TRI, bool CKLIM, bool EXPSUM, typename OutT>
__global__ __launch_bounds__(256) void gemm_bt(
    const __bf16* __restrict__ A, long strideA, int lda,
    const __bf16* __restrict__ B, long strideB, int ldb,
    OutT* __restrict__ C, long strideC, int ldc,
    float* __restrict__ gsum,
    int K, float alpha)
{
    __shared__ __bf16 sA[2][128 * 64];
    __shared__ __bf16 sB[2][128 * 64];
    __shared__ float csum[128];

    const int tid = threadIdx.x;
    const int L = blockIdx.x;
    const int per = gridDim.x >> 3;
    const int wrk = (L & 7) * per + (L >> 3);
    int n0, m0, z;
    if (TRI) {
        const int Lt = wrk % 136;
        z = wrk / 136;
        int tb = (int)((sqrtf(8.f * Lt + 1.f) - 1.f) * 0.5f);
        while ((tb + 1) * (tb + 2) / 2 <= Lt) ++tb;
        while (tb * (tb + 1) / 2 > Lt) --tb;
        const int sb = Lt - tb * (tb + 1) / 2;
        n0 = tb * 128;
        m0 = sb * 128;
    } else {
        n0 = (wrk & 7) * 128;
        m0 = ((wrk >> 3) & 15) * 128;
        z  = wrk >> 7;
    }

    const __bf16* Ag = A + (long)z * strideA + (long)m0 * lda;
    const __bf16* Bg = B + (long)z * strideB + (long)n0 * ldb;
    C += (long)z * strideC;
    if (EXPSUM) {
        gsum += (long)z * SEQ;
        if (tid < 128) csum[tid] = 0.f;
    }

    const int lane = tid & 63;
    const int l15  = lane & 15;
    const int quad = lane >> 4;
    const int wave = tid >> 6;
    const int wm = (wave >> 1) * 64;
    const int wn = (wave & 1) * 64;

    f32x4 acc[4][4];
    const f32x4 zero = {0.f, 0.f, 0.f, 0.f};
#pragma unroll
    for (int i = 0; i < 4; ++i)
#pragma unroll
        for (int j = 0; j < 4; ++j) acc[i][j] = zero;

    const int Kend = CKLIM ? min(K, m0 + 128) : K;

    stage_tile(Ag, lda, sA[0], tid);
    stage_tile(Bg, ldb, sB[0], tid);
    __syncthreads();

    int cur = 0;
    for (int kc = 0; kc < Kend; kc += 64) {
        const int nxt = kc + 64;
        if (nxt < Kend) {
            stage_tile(Ag + nxt, lda, sA[cur ^ 1], tid);
            stage_tile(Bg + nxt, ldb, sB[cur ^ 1], tid);
        }
        mfma_ktile(sA[cur], sB[cur], wm, wn, l15, quad, acc);
        __syncthreads();
        cur ^= 1;
    }

#pragma unroll
    for (int j = 0; j < 4; ++j) {
        const int col = n0 + wn + j * 16 + l15;
        float part = 0.f;
#pragma unroll
        for (int i = 0; i < 4; ++i) {
#pragma unroll
            for (int r = 0; r < 4; ++r) {
                const int row = m0 + wm + i * 16 + quad * 4 + r;
                float v = acc[i][j][r] * alpha;
                if (EXPSUM) {
                    v = __expf(v);
                    if (row <= col) part += v;
                }
                C[(long)row * ldc + col] = (OutT)v;
            }
        }
        if (EXPSUM) atomicAdd(&csum[wn + j * 16 + l15], part);
    }
    if (EXPSUM) {
        __syncthreads();
        if (tid < 128) atomicAdd(&gsum[n0 + tid], csum[tid]);
    }
}

template <typename ET>
__global__ __launch_bounds__(256) void scale_emit(
    const ET* __restrict__ E, float* __restrict__ Out,
    const float* __restrict__ csum, __bf16* __restrict__ AT)
{
    __shared__ __bf16 tile[64][65];
    const int b = blockIdx.z;
    const int t0 = blockIdx.x * 128;
    const int s0 = blockIdx.y * 128;
    const ET* Eb = E + (long)b * SEQ * SEQ;
    float* Ob = Out + (long)b * SEQ * SEQ;
    __bf16* Ab = AT + (long)b * SEQ * SEQ;
    const int tid = threadIdx.x;

    if (s0 > t0 + 127) {
        const f32x4 z4 = {0.f, 0.f, 0.f, 0.f};
        const int c4 = (tid & 31) * 4;
        for (int r = tid >> 5; r < 128; r += 8)
            *(f32x4*)&Ob[(long)(s0 + r) * SEQ + t0 + c4] = z4;
        return;
    }

#pragma unroll
    for (int ds = 0; ds < 2; ++ds) {
#pragma unroll
        for (int dt = 0; dt < 2; ++dt) {
            const int ss = s0 + ds * 64, tt = t0 + dt * 64;
            const int c4 = (tid & 15) * 4;
            const int tcol = tt + c4;
            const f32x4 sv = *(const f32x4*)&csum[(long)b * SEQ + tcol];
            f32x4 inv;
#pragma unroll
            for (int k = 0; k < 4; ++k) inv[k] = 1.0f / sv[k];
#pragma unroll
            for (int r0 = 0; r0 < 64; r0 += 16) {
                const int s = ss + r0 + (tid >> 4);
                f32x4 e = load4f(&Eb[(long)s * SEQ + tcol]);
                f32x4 p;
#pragma unroll
                for (int k = 0; k < 4; ++k)
                    p[k] = (s <= tcol + k) ? e[k] * inv[k] : 0.f;
                *(f32x4*)&Ob[(long)s * SEQ + tcol] = p;
#pragma unroll
                for (int k = 0; k < 4; ++k)
                    tile[r0 + (tid >> 4)][c4 + k] = (__bf16)p[k];
            }
            __syncthreads();
            const int tr = tid >> 2;
            const int sc = (tid & 3) * 16;
            __bf16 v[16];
#pragma unroll
            for (int jj = 0; jj < 16; ++jj) v[jj] = tile[sc + jj][tr];
            *(bf16x8*)&Ab[(long)(tt + tr) * SEQ + ss + sc]     = *(bf16x8*)v;
            *(bf16x8*)&Ab[(long)(tt + tr) * SEQ + ss + sc + 8] = *(bf16x8*)(v + 8);
            __syncthreads();
        }
    }
}

// ---------------------------------------------------------------------------
// Batched f32 -> bf16 convert: up to 6 jobs in one dispatch.
// ---------------------------------------------------------------------------
struct CvtJob { const float* in; __bf16* out; int nblk; };
struct Cvt6 { CvtJob j[6]; };
__global__ __launch_bounds__(256) void cvt_bf16(Cvt6 c)
{
    const CvtJob jb = c.j[blockIdx.y];
    if ((int)blockIdx.x >= jb.nblk) return;
    const long i = ((long)blockIdx.x * 256 + threadIdx.x) * 8;
    *(bf16x8*)&jb.out[i] = load8cvt(&jb.in[i]);
}

// ---------------------------------------------------------------------------
extern "C" void kernel_launch(void* const* d_in, const int* in_sizes, int n_in,
                              void* d_out, int out_size, void* d_ws, size_t ws_size,
                              hipStream_t stream)
{
    const float* queries = (const float*)d_in[0];
    const float* keys    = (const float*)d_in[1];
    const float* values  = (const float*)d_in[2];
    const float* Wq = (const float*)d_in[3];
    const float* bq = (const float*)d_in[4];
    const float* Wk = (const float*)d_in[5];
    const float* bk = (const float*)d_in[6];
    const float* Wv = (const float*)d_in[7];
    const float* bv = (const float*)d_in[8];

    const long tokens = (long)NB * SEQ;           // 8192
    const long pe = tokens * HD;                  // elems per 16 MiB buffer
    const size_t SLOT = (size_t)pe * sizeof(__bf16);   // 16 MiB
    const int WBLK = WEL / 2048;                  // 512 cvt blocks per weight

    float* outCtx  = (float*)d_out;               // [4][2048][1024] f32
    float* outAttn = outCtx + tokens * HD;        // [4][2048][2048] f32
    __bf16* wb = (__bf16*)outAttn;                // bf16 weights: dead-at-start
    __bf16* Wqb = wb, *Wkb = wb + WEL, *Wvb = wb + 2 * WEL;

    const dim3 blk(256);
    char* w = (char*)d_ws;
    __bf16 *qp, *kp, *vT;

    // weights-only convert (12MB read / 6MB write)
    Cvt6 cvw = {{{Wq, Wqb, WBLK}, {Wk, Wkb, WBLK}, {Wv, Wvb, WBLK},
                 {nullptr, nullptr, 0}, {nullptr, nullptr, 0}, {nullptr, nullptr, 0}}};

    if (ws_size >= 6 * SLOT) {
        // [Et0][Et1][colsum...][qp][kp][vT]; proj reads f32 activations direct.
        qp = (__bf16*)(w + 3 * SLOT);
        kp = (__bf16*)(w + 4 * SLOT);
        vT = (__bf16*)(w + 5 * SLOT);
        __bf16* Ebf = (__bf16*)w;                 // slots 0-1
        float* colsum = (float*)(w + 2 * SLOT);   // slot 2

        hipMemsetAsync(colsum, 0, (size_t)NB * SEQ * sizeof(float), stream);
        cvt_bf16<<<dim3(WBLK, 3), blk, 0, stream>>>(cvw);
        Proj3 pj = {{queries, keys, values}, {Wqb, Wkb, Wvb}, {bq, bk, bv},
                    {qp, kp, vT}, 4};
        gemm_projF<<<dim3(512 * 3), blk, 0, stream>>>(pj);

        // Et[b][t][s] = exp(<q_t,k_s>/32) masked; rowsums into colsum
        gemm_sc<__bf16><<<dim3(544), blk, 0, stream>>>(qp, kp, Ebf, colsum, 0.03125f);
        // f32 attn output (transposed, normalized)
        emit_attn<<<dim3(SEQ / 128, SEQ / 128, NB), blk, 0, stream>>>(
            Ebf, outAttn, colsum);
        // context with per-row normalization in epilogue
        gemm_ctx<<<dim3(512), blk, 0, stream>>>(Ebf, vT, outCtx, colsum);
    } else if (ws_size >= 4 * SLOT) {
        // [qp][kp][vT][unused]; attnT aliases qp+kp (dead after scores);
        // E stays f32 in outAttn (in-place scale_emit). Legacy downstream.
        float* colsum = outCtx;
        hipMemsetAsync(colsum, 0, (size_t)NB * SEQ * sizeof(float), stream);
        qp = (__bf16*)w;
        kp = (__bf16*)(w + SLOT);
        vT = (__bf16*)(w + 2 * SLOT);
        __bf16* attnT = (__bf16*)d_ws;            // slots 0-1 after scores

        cvt_bf16<<<dim3(WBLK, 3), blk, 0, stream>>>(cvw);
        Proj3 pj = {{queries, keys, values}, {Wqb, Wkb, Wvb}, {bq, bk, bv},
                    {qp, kp, vT}, 4};
        gemm_projF<<<dim3(512 * 3), blk, 0, stream>>>(pj);

        gemm_bt<true, false, true, float><<<dim3(544), blk, 0, stream>>>(
            kp, (long)SEQ * HD, HD, qp, (long)SEQ * HD, HD,
            outAttn, (long)SEQ * SEQ, SEQ, colsum, HD, 0.03125f);
        scale_emit<float><<<dim3(SEQ / 128, SEQ / 128, NB), blk, 0, stream>>>(
            outAttn, outAttn, colsum, attnT);
        gemm_bt<false, true, false, float><<<dim3(512), blk, 0, stream>>>(
            attnT, (long)SEQ * SEQ, SEQ, vT, (long)HD * SEQ, SEQ,
            outCtx, (long)SEQ * HD, HD, nullptr, SEQ, 1.0f);
    } else {
        // fallback: f32-staged operands straight from inputs; [qp][kp][vT]
        float* colsum = outCtx;
        hipMemsetAsync(colsum, 0, (size_t)NB * SEQ * sizeof(float), stream);
        qp = (__bf16*)w;
        kp = (__bf16*)(w + SLOT);
        vT = (__bf16*)(w + 2 * SLOT);
        __bf16* attnT = (__bf16*)d_ws;
        Proj3 pj = {{queries, keys, values}, {Wq, Wk, Wv}, {bq, bk, bv},
                    {qp, kp, vT}, 4};
        gemm_proj<float, float><<<dim3(512 * 3), blk, 0, stream>>>(pj);

        gemm_bt<true, false, true, float><<<dim3(544), blk, 0, stream>>>(
            kp, (long)SEQ * HD, HD, qp, (long)SEQ * HD, HD,
            outAttn, (long)SEQ * SEQ, SEQ, colsum, HD, 0.03125f);
        scale_emit<float><<<dim3(SEQ / 128, SEQ / 128, NB), blk, 0, stream>>>(
            outAttn, outAttn, colsum, attnT);
        gemm_bt<false, true, false, float><<<dim3(512), blk, 0, stream>>>(
            attnT, (long)SEQ * SEQ, SEQ, vT, (long)HD * SEQ, SEQ,
            outCtx, (long)SEQ * HD, HD, nullptr, SEQ, 1.0f);
    }
}

// Round 9
// 374.230 us; speedup vs baseline: 1.0249x; 1.0158x over previous
//
#include <hip/hip_runtime.h>
#include <math.h>

typedef __bf16 bf16x8 __attribute__((ext_vector_type(8)));
typedef __bf16 bf16x4 __attribute__((ext_vector_type(4)));
typedef float f32x4 __attribute__((ext_vector_type(4)));

#define HD 1024
#define SEQ 2048
#define NB 4
#define WEL (HD * HD)   // elements per weight matrix

// NOTE (R6-R8 closed arc): fusing the f32->bf16 activation convert into the
// projection GEMM (reg-staged f32 A) is a dead end on this structure. The
// chain: (a) LLVM MachineSink sinks cross-BB loads to first use, defeating
// sched_barrier (VGPR tell: stays 88); (b) straight-line body makes fences
// partially bind (VGPR 100) but dur unchanged at 146us because (c) the fused
// kernel is ACHIEVED-BANDWIDTH limited: 126MB at ~860GB/s = 146us exactly —
// 2 blocks/CU of reg-staged loads can't fill more BW. Split cvt (streaming,
// multi-TB/s) + bf16 proj (101us) sums to ~130us < 146us fused.

// Load 8 contiguous elements as bf16x8, converting f32 -> bf16 if needed.
__device__ inline bf16x8 load8cvt(const __bf16* p) { return *(const bf16x8*)p; }
__device__ inline bf16x8 load8cvt(const float* p) {
    f32x4 a = *(const f32x4*)p;
    f32x4 b = *(const f32x4*)(p + 4);
    bf16x8 r;
#pragma unroll
    for (int i = 0; i < 4; ++i) { r[i] = (__bf16)a[i]; r[i + 4] = (__bf16)b[i]; }
    return r;
}

// Load 4 contiguous elements as f32x4 (from f32 or bf16 source).
__device__ inline f32x4 load4f(const float* p) { return *(const f32x4*)p; }
__device__ inline f32x4 load4f(const __bf16* p) {
    bf16x4 v = *(const bf16x4*)p;
    f32x4 r;
#pragma unroll
    for (int i = 0; i < 4; ++i) r[i] = (float)v[i];
    return r;
}

// Async global->LDS, 16 bytes per lane (global_load_lds_dwordx4).
__device__ inline void gld_lds16(const void* g, void* l) {
    __builtin_amdgcn_global_load_lds(
        (const __attribute__((address_space(1))) unsigned int*)g,
        (__attribute__((address_space(3))) unsigned int*)l, 16, 0, 0);
}

// ===========================================================================
// 128x128 BK=64 tile machinery (shared by all GEMMs). XOR-swizzled LDS tile:
// LDS chunk (row, j) holds GLOBAL chunk (row, j ^ (row&7)); global source is
// pre-swizzled so the LDS destination stays linear (global_load_lds rule).
// ===========================================================================
template <typename T>
__device__ inline void stage_tile(const T* __restrict__ G, int ld, __bf16* s, int tid)
{
    const int r  = tid >> 3;                          // 0..31
    const int co = ((tid & 7) ^ (r & 7)) * 8;         // swizzled source column
    if constexpr (sizeof(T) == 2) {
        __bf16* dst = s + (tid >> 6) * 512;           // wave-uniform base
#pragma unroll
        for (int c = 0; c < 4; ++c)
            gld_lds16(G + (long)(c * 32 + r) * ld + co, dst + c * 2048);
    } else {
#pragma unroll
        for (int c = 0; c < 4; ++c)
            *(bf16x8*)(s + c * 2048 + tid * 8) = load8cvt(G + (long)(c * 32 + r) * ld + co);
    }
}

__device__ inline bf16x8 frag_read(const __bf16* s, int row, int c)
{
    return *(const bf16x8*)&s[row * 64 + ((c ^ (row & 7)) * 8)];
}

__device__ inline void mfma_ktile(const __bf16* __restrict__ sa,
                                  const __bf16* __restrict__ sb,
                                  int wm, int wn, int l15, int quad,
                                  f32x4 (&acc)[4][4])
{
#pragma unroll
    for (int kk = 0; kk < 64; kk += 32) {
        const int c8 = quad + (kk >> 3);
        bf16x8 af[4], bf[4];
#pragma unroll
        for (int i = 0; i < 4; ++i)
            af[i] = frag_read(sa, wm + i * 16 + l15, c8);
#pragma unroll
        for (int j = 0; j < 4; ++j)
            bf[j] = frag_read(sb, wn + j * 16 + l15, c8);
#pragma unroll
        for (int i = 0; i < 4; ++i)
#pragma unroll
            for (int j = 0; j < 4; ++j)
                acc[i][j] = __builtin_amdgcn_mfma_f32_16x16x32_bf16(af[i], bf[j], acc[i][j], 0, 0, 0);
    }
}

// ===========================================================================
// Projection GEMM (R1 double-buffered structure — best measured: 101.4 us).
// Z-batched: C_z[m,n] = sum_k A_z[m,k]*W_z[n,k] + bias_z[n]; vtmask bit z =>
// transposed scatter-store vT[b][n][s]. Grid 512*nz, XCD-remapped.
// ===========================================================================
struct Proj3 {
    const void* A[3];
    const void* W[3];
    const float* bias[3];
    __bf16* C[3];
    int vtmask;
};

template <typename TA, typename TW>
__global__ __launch_bounds__(256) void gemm_proj(Proj3 p)
{
    __shared__ __bf16 sA[2][128 * 64];
    __shared__ __bf16 sB[2][128 * 64];

    const int tid = threadIdx.x;
    const int L = blockIdx.x;
    const int per = gridDim.x >> 3;
    const int wrk = (L & 7) * per + (L >> 3);
    const int n0 = (wrk & 7) * 128;
    const int m0 = ((wrk >> 3) & 63) * 128;
    const int z  = wrk >> 9;
    const bool vt = (p.vtmask >> z) & 1;

    const TA* Ag = (const TA*)p.A[z] + (long)m0 * HD;
    const TW* Wg = (const TW*)p.W[z] + (long)n0 * HD;
    const float* bias = p.bias[z];
    __bf16* C = p.C[z];

    const int lane = tid & 63;
    const int l15  = lane & 15;
    const int quad = lane >> 4;
    const int wave = tid >> 6;
    const int wm = (wave >> 1) * 64;
    const int wn = (wave & 1) * 64;

    f32x4 acc[4][4];
    const f32x4 zero = {0.f, 0.f, 0.f, 0.f};
#pragma unroll
    for (int i = 0; i < 4; ++i)
#pragma unroll
        for (int j = 0; j < 4; ++j) acc[i][j] = zero;

    stage_tile(Ag, HD, sA[0], tid);
    stage_tile(Wg, HD, sB[0], tid);
    __syncthreads();

    int cur = 0;
    for (int kc = 0; kc < HD; kc += 64) {
        const int nxt = kc + 64;
        if (nxt < HD) {                       // issue next tile's loads first
            stage_tile(Ag + nxt, HD, sA[cur ^ 1], tid);
            stage_tile(Wg + nxt, HD, sB[cur ^ 1], tid);
        }
        mfma_ktile(sA[cur], sB[cur], wm, wn, l15, quad, acc);
        __syncthreads();
        cur ^= 1;
    }

#pragma unroll
    for (int j = 0; j < 4; ++j) {
        const int col = n0 + wn + j * 16 + l15;
        const float bv = bias[col];
#pragma unroll
        for (int i = 0; i < 4; ++i) {
#pragma unroll
            for (int r = 0; r < 4; ++r) {
                const int row = m0 + wm + i * 16 + quad * 4 + r;
                const float v = acc[i][j][r] + bv;
                if (vt) {
                    C[(((long)(row >> 11) * HD) + col) * SEQ + (row & (SEQ - 1))] = (__bf16)v;
                } else {
                    C[(long)row * HD + col] = (__bf16)v;
                }
            }
        }
    }
}

// ---------------------------------------------------------------------------
// Scores GEMM, [t][s] layout: Et[t][s] = exp(<q_t,k_s>*alpha) for s<=t, else 0.
// A=qp (rows t), B=kp (rows s). TRI blocks: m0 = tb*128 (t) >= n0 = sb*128 (s).
// Row-sums (softmax denominators, per t) accumulated via shfl-reduce + atomics.
// ---------------------------------------------------------------------------
template <typename OutT>
__global__ __launch_bounds__(256) void gemm_sc(
    const __bf16* __restrict__ A, const __bf16* __restrict__ B,
    OutT* __restrict__ C, float* __restrict__ gsum, float alpha)
{
    __shared__ __bf16 s1[2][128 * 64];
    __shared__ __bf16 s2[2][128 * 64];
    __shared__ float csum[128];

    const int tid = threadIdx.x;
    const int L = blockIdx.x;
    const int per = gridDim.x >> 3;
    const int wrk = (L & 7) * per + (L >> 3);
    const int Lt = wrk % 136;
    const int z  = wrk / 136;
    int tb = (int)((sqrtf(8.f * Lt + 1.f) - 1.f) * 0.5f);
    while ((tb + 1) * (tb + 2) / 2 <= Lt) ++tb;
    while (tb * (tb + 1) / 2 > Lt) --tb;
    const int sb = Lt - tb * (tb + 1) / 2;
    const int m0 = tb * 128;      // t (row), tb >= sb
    const int n0 = sb * 128;      // s (col)

    const __bf16* Ag = A + (long)z * SEQ * HD + (long)m0 * HD;
    const __bf16* Bg = B + (long)z * SEQ * HD + (long)n0 * HD;
    C += (long)z * SEQ * SEQ;
    gsum += (long)z * SEQ;
    if (tid < 128) csum[tid] = 0.f;    // visible after first __syncthreads

    const int lane = tid & 63, l15 = lane & 15, quad = lane >> 4;
    const int wave = tid >> 6;
    const int wm = (wave >> 1) * 64;
    const int wn = (wave & 1) * 64;

    f32x4 acc[4][4];
    const f32x4 zero = {0.f, 0.f, 0.f, 0.f};
#pragma unroll
    for (int i = 0; i < 4; ++i)
#pragma unroll
        for (int j = 0; j < 4; ++j) acc[i][j] = zero;

    stage_tile(Ag, HD, s1[0], tid);
    stage_tile(Bg, HD, s2[0], tid);
    __syncthreads();
    int cur = 0;
    for (int kc = 0; kc < HD; kc += 64) {
        const int nxt = kc + 64;
        if (nxt < HD) {
            stage_tile(Ag + nxt, HD, s1[cur ^ 1], tid);
            stage_tile(Bg + nxt, HD, s2[cur ^ 1], tid);
        }
        mfma_ktile(s1[cur], s2[cur], wm, wn, l15, quad, acc);
        __syncthreads();
        cur ^= 1;
    }

    float rsum[4][4];
#pragma unroll
    for (int i = 0; i < 4; ++i)
#pragma unroll
        for (int r = 0; r < 4; ++r) rsum[i][r] = 0.f;

#pragma unroll
    for (int j = 0; j < 4; ++j) {
        const int col = n0 + wn + j * 16 + l15;
#pragma unroll
        for (int i = 0; i < 4; ++i) {
#pragma unroll
            for (int r = 0; r < 4; ++r) {
                const int row = m0 + wm + i * 16 + quad * 4 + r;
                const float e = (col <= row) ? __expf(acc[i][j][r] * alpha) : 0.f;
                C[(long)row * SEQ + col] = (OutT)e;
                rsum[i][r] += e;
            }
        }
    }
#pragma unroll
    for (int i = 0; i < 4; ++i) {
#pragma unroll
        for (int r = 0; r < 4; ++r) {
            float v = rsum[i][r];
            v += __shfl_xor(v, 1); v += __shfl_xor(v, 2);
            v += __shfl_xor(v, 4); v += __shfl_xor(v, 8);
            if (l15 == 0) atomicAdd(&csum[wm + i * 16 + quad * 4 + r], v);
        }
    }
    __syncthreads();
    if (tid < 128) atomicAdd(&gsum[m0 + tid], csum[tid]);
}

// ---------------------------------------------------------------------------
// Context GEMM: C[t][h] = inv[t] * sum_{s<=t} Et[t][s] * vT[h][s].
// A=Et (lda=SEQ), B=vT (ldb=SEQ), causal K-limit Kend=m0+128, per-row scale
// from gsum in epilogue. m-block index goes through the pairing bijection
// 0,15,1,14,... so consecutively-dispatched blocks pair long+short K (each
// adjacent pair sums to a uniform 2176 K-rows) -> balanced CU residency.
// ---------------------------------------------------------------------------
__global__ __launch_bounds__(256) void gemm_ctx(
    const __bf16* __restrict__ A, const __bf16* __restrict__ B,
    float* __restrict__ C, const float* __restrict__ gsum)
{
    __shared__ __bf16 s1[2][128 * 64];
    __shared__ __bf16 s2[2][128 * 64];
    __shared__ float rs[128];

    const int tid = threadIdx.x;
    const int L = blockIdx.x;
    const int per = gridDim.x >> 3;
    const int wrk = (L & 7) * per + (L >> 3);
    const int n0 = (wrk & 7) * 128;          // h
    const int q  = (wrk >> 3) & 15;
    const int mb = (q & 1) ? (15 - (q >> 1)) : (q >> 1);   // 0,15,1,14,...
    const int m0 = mb * 128;                 // t
    const int z  = wrk >> 7;

    const __bf16* Ag = A + (long)z * SEQ * SEQ + (long)m0 * SEQ;
    const __bf16* Bg = B + (long)z * HD * SEQ + (long)n0 * SEQ;
    C += (long)z * SEQ * HD;
    if (tid < 128) rs[tid] = gsum[(long)z * SEQ + m0 + tid];

    const int lane = tid & 63, l15 = lane & 15, quad = lane >> 4;
    const int wave = tid >> 6;
    const int wm = (wave >> 1) * 64;
    const int wn = (wave & 1) * 64;

    f32x4 acc[4][4];
    const f32x4 zero = {0.f, 0.f, 0.f, 0.f};
#pragma unroll
    for (int i = 0; i < 4; ++i)
#pragma unroll
        for (int j = 0; j < 4; ++j) acc[i][j] = zero;

    const int Kend = m0 + 128;

    stage_tile(Ag, SEQ, s1[0], tid);
    stage_tile(Bg, SEQ, s2[0], tid);
    __syncthreads();
    int cur = 0;
    for (int kc = 0; kc < Kend; kc += 64) {
        const int nxt = kc + 64;
        if (nxt < Kend) {
            stage_tile(Ag + nxt, SEQ, s1[cur ^ 1], tid);
            stage_tile(Bg + nxt, SEQ, s2[cur ^ 1], tid);
        }
        mfma_ktile(s1[cur], s2[cur], wm, wn, l15, quad, acc);
        __syncthreads();
        cur ^= 1;
    }

    float invr[4][4];
#pragma unroll
    for (int i = 0; i < 4; ++i)
#pragma unroll
        for (int r = 0; r < 4; ++r)
            invr[i][r] = 1.0f / rs[wm + i * 16 + quad * 4 + r];

#pragma unroll
    for (int j = 0; j < 4; ++j) {
        const int col = n0 + wn + j * 16 + l15;
#pragma unroll
        for (int i = 0; i < 4; ++i) {
#pragma unroll
            for (int r = 0; r < 4; ++r) {
                const int row = m0 + wm + i * 16 + quad * 4 + r;
                C[(long)row * HD + col] = acc[i][j][r] * invr[i][r];
            }
        }
    }
}

// ---------------------------------------------------------------------------
// Emit f32 attention output: Out[s][t] = Et[t][s] * inv[t]. 128x128 per block,
// 2x2 64x64 LDS-transposed subtiles; tile padded to [64][68]; global stores
// arranged so each 4-lane cluster writes 64B contiguous.
// ---------------------------------------------------------------------------
__global__ __launch_bounds__(256) void emit_attn(
    const __bf16* __restrict__ Et, float* __restrict__ Out,
    const float* __restrict__ csum)
{
    __shared__ float tile[64][68];
    const int b = blockIdx.z;
    const int t0 = blockIdx.x * 128;
    const int s0 = blockIdx.y * 128;
    const __bf16* Eb = Et + (long)b * SEQ * SEQ;
    float* Ob = Out + (long)b * SEQ * SEQ;
    const int tid = threadIdx.x;

    if (s0 > t0 + 127) {     // fully masked: zero-fill f32 output
        const f32x4 z4 = {0.f, 0.f, 0.f, 0.f};
        const int c4 = (tid & 31) * 4;
        for (int r = tid >> 5; r < 128; r += 8)
            *(f32x4*)&Ob[(long)(s0 + r) * SEQ + t0 + c4] = z4;
        return;
    }

#pragma unroll
    for (int dt = 0; dt < 2; ++dt) {
#pragma unroll
        for (int dsb = 0; dsb < 2; ++dsb) {
            const int tt = t0 + dt * 64, ss = s0 + dsb * 64;
            const int c4 = (tid & 15) * 4;
#pragma unroll
            for (int r0 = 0; r0 < 64; r0 += 16) {
                const int tl = r0 + (tid >> 4);
                const float inv = 1.0f / csum[(long)b * SEQ + tt + tl];
                f32x4 e = load4f(&Eb[(long)(tt + tl) * SEQ + ss + c4]);
#pragma unroll
                for (int k = 0; k < 4; ++k) tile[tl][c4 + k] = e[k] * inv;
            }
            __syncthreads();
            const int sl = tid >> 2;            // 0..63 (s-local row)
            const int t4 = (tid & 3) * 4;       // cluster offset within 16-col group
#pragma unroll
            for (int qq = 0; qq < 4; ++qq) {
                f32x4 ov;
#pragma unroll
                for (int k = 0; k < 4; ++k) ov[k] = tile[qq * 16 + t4 + k][sl];
                *(f32x4*)&Ob[(long)(ss + sl) * SEQ + tt + qq * 16 + t4] = ov;
            }
            __syncthreads();
        }
    }
}

// ===========================================================================
// Legacy kernels (mid / fallback workspace paths) — unchanged semantics.
// ===========================================================================
template <bool TRI, bool CKLIM, bool EXPSUM, typename OutT>
__global__ __launch_bounds__(256) void gemm_bt(
    const __bf16* __restrict__ A, long strideA, int lda,
    const __bf16* __restrict__ B, long strideB, int ldb,
    OutT* __restrict__ C, long strideC, int ldc,
    float* __restrict__ gsum,
    int K, float alpha)
{
    __shared__ __bf16 sA[2][128 * 64];
    __shared__ __bf16 sB[2][128 * 64];
    __shared__ float csum[128];

    const int tid = threadIdx.x;
    const int L = blockIdx.x;
    const int per = gridDim.x >> 3;
    const int wrk = (L & 7) * per + (L >> 3);
    int n0, m0, z;
    if (TRI) {
        const int Lt = wrk % 136;
        z = wrk / 136;
        int tb = (int)((sqrtf(8.f * Lt + 1.f) - 1.f) * 0.5f);
        while ((tb + 1) * (tb + 2) / 2 <= Lt) ++tb;
        while (tb * (tb + 1) / 2 > Lt) --tb;
        const int sb = Lt - tb * (tb + 1) / 2;
        n0 = tb * 128;
        m0 = sb * 128;
    } else {
        n0 = (wrk & 7) * 128;
        m0 = ((wrk >> 3) & 15) * 128;
        z  = wrk >> 7;
    }

    const __bf16* Ag = A + (long)z * strideA + (long)m0 * lda;
    const __bf16* Bg = B + (long)z * strideB + (long)n0 * ldb;
    C += (long)z * strideC;
    if (EXPSUM) {
        gsum += (long)z * SEQ;
        if (tid < 128) csum[tid] = 0.f;
    }

    const int lane = tid & 63;
    const int l15  = lane & 15;
    const int quad = lane >> 4;
    const int wave = tid >> 6;
    const int wm = (wave >> 1) * 64;
    const int wn = (wave & 1) * 64;

    f32x4 acc[4][4];
    const f32x4 zero = {0.f, 0.f, 0.f, 0.f};
#pragma unroll
    for (int i = 0; i < 4; ++i)
#pragma unroll
        for (int j = 0; j < 4; ++j) acc[i][j] = zero;

    const int Kend = CKLIM ? min(K, m0 + 128) : K;

    stage_tile(Ag, lda, sA[0], tid);
    stage_tile(Bg, ldb, sB[0], tid);
    __syncthreads();

    int cur = 0;
    for (int kc = 0; kc < Kend; kc += 64) {
        const int nxt = kc + 64;
        if (nxt < Kend) {
            stage_tile(Ag + nxt, lda, sA[cur ^ 1], tid);
            stage_tile(Bg + nxt, ldb, sB[cur ^ 1], tid);
        }
        mfma_ktile(sA[cur], sB[cur], wm, wn, l15, quad, acc);
        __syncthreads();
        cur ^= 1;
    }

#pragma unroll
    for (int j = 0; j < 4; ++j) {
        const int col = n0 + wn + j * 16 + l15;
        float part = 0.f;
#pragma unroll
        for (int i = 0; i < 4; ++i) {
#pragma unroll
            for (int r = 0; r < 4; ++r) {
                const int row = m0 + wm + i * 16 + quad * 4 + r;
                float v = acc[i][j][r] * alpha;
                if (EXPSUM) {
                    v = __expf(v);
                    if (row <= col) part += v;
                }
                C[(long)row * ldc + col] = (OutT)v;
            }
        }
        if (EXPSUM) atomicAdd(&csum[wn + j * 16 + l15], part);
    }
    if (EXPSUM) {
        __syncthreads();
        if (tid < 128) atomicAdd(&gsum[n0 + tid], csum[tid]);
    }
}

template <typename ET>
__global__ __launch_bounds__(256) void scale_emit(
    const ET* __restrict__ E, float* __restrict__ Out,
    const float* __restrict__ csum, __bf16* __restrict__ AT)
{
    __shared__ __bf16 tile[64][65];
    const int b = blockIdx.z;
    const int t0 = blockIdx.x * 128;
    const int s0 = blockIdx.y * 128;
    const ET* Eb = E + (long)b * SEQ * SEQ;
    float* Ob = Out + (long)b * SEQ * SEQ;
    __bf16* Ab = AT + (long)b * SEQ * SEQ;
    const int tid = threadIdx.x;

    if (s0 > t0 + 127) {
        const f32x4 z4 = {0.f, 0.f, 0.f, 0.f};
        const int c4 = (tid & 31) * 4;
        for (int r = tid >> 5; r < 128; r += 8)
            *(f32x4*)&Ob[(long)(s0 + r) * SEQ + t0 + c4] = z4;
        return;
    }

#pragma unroll
    for (int ds = 0; ds < 2; ++ds) {
#pragma unroll
        for (int dt = 0; dt < 2; ++dt) {
            const int ss = s0 + ds * 64, tt = t0 + dt * 64;
            const int c4 = (tid & 15) * 4;
            const int tcol = tt + c4;
            const f32x4 sv = *(const f32x4*)&csum[(long)b * SEQ + tcol];
            f32x4 inv;
#pragma unroll
            for (int k = 0; k < 4; ++k) inv[k] = 1.0f / sv[k];
#pragma unroll
            for (int r0 = 0; r0 < 64; r0 += 16) {
                const int s = ss + r0 + (tid >> 4);
                f32x4 e = load4f(&Eb[(long)s * SEQ + tcol]);
                f32x4 p;
#pragma unroll
                for (int k = 0; k < 4; ++k)
                    p[k] = (s <= tcol + k) ? e[k] * inv[k] : 0.f;
                *(f32x4*)&Ob[(long)s * SEQ + tcol] = p;
#pragma unroll
                for (int k = 0; k < 4; ++k)
                    tile[r0 + (tid >> 4)][c4 + k] = (__bf16)p[k];
            }
            __syncthreads();
            const int tr = tid >> 2;
            const int sc = (tid & 3) * 16;
            __bf16 v[16];
#pragma unroll
            for (int jj = 0; jj < 16; ++jj) v[jj] = tile[sc + jj][tr];
            *(bf16x8*)&Ab[(long)(tt + tr) * SEQ + ss + sc]     = *(bf16x8*)v;
            *(bf16x8*)&Ab[(long)(tt + tr) * SEQ + ss + sc + 8] = *(bf16x8*)(v + 8);
            __syncthreads();
        }
    }
}

// ---------------------------------------------------------------------------
// Batched f32 -> bf16 convert: up to 6 jobs in one dispatch.
// ---------------------------------------------------------------------------
struct CvtJob { const float* in; __bf16* out; int nblk; };
struct Cvt6 { CvtJob j[6]; };
__global__ __launch_bounds__(256) void cvt_bf16(Cvt6 c)
{
    const CvtJob jb = c.j[blockIdx.y];
    if ((int)blockIdx.x >= jb.nblk) return;
    const long i = ((long)blockIdx.x * 256 + threadIdx.x) * 8;
    *(bf16x8*)&jb.out[i] = load8cvt(&jb.in[i]);
}

// ---------------------------------------------------------------------------
extern "C" void kernel_launch(void* const* d_in, const int* in_sizes, int n_in,
                              void* d_out, int out_size, void* d_ws, size_t ws_size,
                              hipStream_t stream)
{
    const float* queries = (const float*)d_in[0];
    const float* keys    = (const float*)d_in[1];
    const float* values  = (const float*)d_in[2];
    const float* Wq = (const float*)d_in[3];
    const float* bq = (const float*)d_in[4];
    const float* Wk = (const float*)d_in[5];
    const float* bk = (const float*)d_in[6];
    const float* Wv = (const float*)d_in[7];
    const float* bv = (const float*)d_in[8];

    const long tokens = (long)NB * SEQ;           // 8192
    const long pe = tokens * HD;                  // elems per 16 MiB buffer
    const size_t SLOT = (size_t)pe * sizeof(__bf16);   // 16 MiB
    const int ABLK = (int)(pe / 2048);            // 4096 cvt blocks per activation
    const int WBLK = WEL / 2048;                  // 512 cvt blocks per weight

    float* outCtx  = (float*)d_out;               // [4][2048][1024] f32
    float* outAttn = outCtx + tokens * HD;        // [4][2048][2048] f32
    __bf16* wb = (__bf16*)outAttn;                // bf16 weights: dead-at-start
    __bf16* Wqb = wb, *Wkb = wb + WEL, *Wvb = wb + 2 * WEL;

    const dim3 blk(256);
    char* w = (char*)d_ws;
    __bf16 *qp, *kp, *vT;

    if (ws_size >= 6 * SLOT) {
        // [xq][xk][xv][qp][kp][vT]; after proj: Et bf16 -> slots 0-1,
        // colsum -> slot 2 (xv dead), vT slot 5 stays live.
        __bf16* xq = (__bf16*)w;
        __bf16* xk = (__bf16*)(w + SLOT);
        __bf16* xv = (__bf16*)(w + 2 * SLOT);
        qp = (__bf16*)(w + 3 * SLOT);
        kp = (__bf16*)(w + 4 * SLOT);
        vT = (__bf16*)(w + 5 * SLOT);
        __bf16* Ebf = (__bf16*)w;
        float* colsum = (float*)(w + 2 * SLOT);

        Cvt6 cv = {{{queries, xq, ABLK}, {keys, xk, ABLK}, {values, xv, ABLK},
                    {Wq, Wqb, WBLK}, {Wk, Wkb, WBLK}, {Wv, Wvb, WBLK}}};
        cvt_bf16<<<dim3(ABLK, 6), blk, 0, stream>>>(cv);
        Proj3 pj = {{xq, xk, xv}, {Wqb, Wkb, Wvb}, {bq, bk, bv}, {qp, kp, vT}, 4};
        gemm_proj<__bf16, __bf16><<<dim3(512 * 3), blk, 0, stream>>>(pj);

        hipMemsetAsync(colsum, 0, (size_t)NB * SEQ * sizeof(float), stream);
        // Et[b][t][s] = exp(<q_t,k_s>/32) masked; rowsums into colsum
        gemm_sc<__bf16><<<dim3(544), blk, 0, stream>>>(qp, kp, Ebf, colsum, 0.03125f);
        // f32 attn output (transposed, normalized)
        emit_attn<<<dim3(SEQ / 128, SEQ / 128, NB), blk, 0, stream>>>(
            Ebf, outAttn, colsum);
        // context with per-row normalization in epilogue
        gemm_ctx<<<dim3(512), blk, 0, stream>>>(Ebf, vT, outCtx, colsum);
    } else if (ws_size >= 4 * SLOT) {
        // legacy mid path: [x0][qp][kp][x1->vT]; attnT aliases x0+qp;
        // E stays f32 in outAttn (in-place scale_emit).
        float* colsum = outCtx;
        hipMemsetAsync(colsum, 0, (size_t)NB * SEQ * sizeof(float), stream);
        __bf16* x0 = (__bf16*)w;
        qp = (__bf16*)(w + SLOT);
        kp = (__bf16*)(w + 2 * SLOT);
        __bf16* x1 = (__bf16*)(w + 3 * SLOT);
        vT = x1;
        __bf16* attnT = (__bf16*)d_ws;

        Cvt6 cv = {{{queries, x0, ABLK}, {keys, x1, ABLK},
                    {Wq, Wqb, WBLK}, {Wk, Wkb, WBLK}, {Wv, Wvb, WBLK},
                    {nullptr, nullptr, 0}}};
        cvt_bf16<<<dim3(ABLK, 5), blk, 0, stream>>>(cv);
        Proj3 pqk = {{x0, x1, nullptr}, {Wqb, Wkb, nullptr}, {bq, bk, nullptr},
                     {qp, kp, nullptr}, 0};
        gemm_proj<__bf16, __bf16><<<dim3(512 * 2), blk, 0, stream>>>(pqk);
        Cvt6 cvv = {{{values, x0, ABLK}, {nullptr, nullptr, 0}, {nullptr, nullptr, 0},
                     {nullptr, nullptr, 0}, {nullptr, nullptr, 0}, {nullptr, nullptr, 0}}};
        cvt_bf16<<<dim3(ABLK, 1), blk, 0, stream>>>(cvv);
        Proj3 pv = {{x0, nullptr, nullptr}, {Wvb, nullptr, nullptr},
                    {bv, nullptr, nullptr}, {vT, nullptr, nullptr}, 1};
        gemm_proj<__bf16, __bf16><<<dim3(512), blk, 0, stream>>>(pv);

        gemm_bt<true, false, true, float><<<dim3(544), blk, 0, stream>>>(
            kp, (long)SEQ * HD, HD, qp, (long)SEQ * HD, HD,
            outAttn, (long)SEQ * SEQ, SEQ, colsum, HD, 0.03125f);
        scale_emit<float><<<dim3(SEQ / 128, SEQ / 128, NB), blk, 0, stream>>>(
            outAttn, outAttn, colsum, attnT);
        gemm_bt<false, true, false, float><<<dim3(512), blk, 0, stream>>>(
            attnT, (long)SEQ * SEQ, SEQ, vT, (long)HD * SEQ, SEQ,
            outCtx, (long)SEQ * HD, HD, nullptr, SEQ, 1.0f);
    } else {
        // fallback: f32-staged operands straight from inputs; [qp][kp][vT]
        float* colsum = outCtx;
        hipMemsetAsync(colsum, 0, (size_t)NB * SEQ * sizeof(float), stream);
        qp = (__bf16*)w;
        kp = (__bf16*)(w + SLOT);
        vT = (__bf16*)(w + 2 * SLOT);
        __bf16* attnT = (__bf16*)d_ws;
        Proj3 pj = {{queries, keys, values}, {Wq, Wk, Wv}, {bq, bk, bv},
                    {qp, kp, vT}, 4};
        gemm_proj<float, float><<<dim3(512 * 3), blk, 0, stream>>>(pj);

        gemm_bt<true, false, true, float><<<dim3(544), blk, 0, stream>>>(
            kp, (long)SEQ * HD, HD, qp, (long)SEQ * HD, HD,
            outAttn, (long)SEQ * SEQ, SEQ, colsum, HD, 0.03125f);
        scale_emit<float><<<dim3(SEQ / 128, SEQ / 128, NB), blk, 0, stream>>>(
            outAttn, outAttn, colsum, attnT);
        gemm_bt<false, true, false, float><<<dim3(512), blk, 0, stream>>>(
            attnT, (long)SEQ * SEQ, SEQ, vT, (long)HD * SEQ, SEQ,
            outCtx, (long)SEQ * HD, HD, nullptr, SEQ, 1.0f);
    }
}

// Round 10
// 357.936 us; speedup vs baseline: 1.0715x; 1.0455x over previous
//
#include <hip/hip_runtime.h>
#include <math.h>

typedef __bf16 bf16x8 __attribute__((ext_vector_type(8)));
typedef __bf16 bf16x4 __attribute__((ext_vector_type(4)));
typedef float f32x4 __attribute__((ext_vector_type(4)));

#define HD 1024
#define SEQ 2048
#define NB 4
#define WEL (HD * HD)   // elements per weight matrix

// NOTE (R6-R8 closed arc): fusing the f32->bf16 activation convert into the
// projection GEMM (reg-staged f32 A) is a dead end on this structure:
// (a) MachineSink sinks cross-BB loads to first use (VGPR tell: 88);
// (b) straight-line + fences binds partially (VGPR 100) but dur unchanged
// because (c) the fused kernel is achieved-BW limited: 126MB @ ~860GB/s =
// 146us exactly. Split cvt (streaming) + bf16 proj (101us) wins.
// R9->R10: proj split into 3x512-block dispatches (same work, exact rounds)
// so rocprof top-5 reveals scores/emit/ctx durations.

// Load 8 contiguous elements as bf16x8, converting f32 -> bf16 if needed.
__device__ inline bf16x8 load8cvt(const __bf16* p) { return *(const bf16x8*)p; }
__device__ inline bf16x8 load8cvt(const float* p) {
    f32x4 a = *(const f32x4*)p;
    f32x4 b = *(const f32x4*)(p + 4);
    bf16x8 r;
#pragma unroll
    for (int i = 0; i < 4; ++i) { r[i] = (__bf16)a[i]; r[i + 4] = (__bf16)b[i]; }
    return r;
}

// Load 4 contiguous elements as f32x4 (from f32 or bf16 source).
__device__ inline f32x4 load4f(const float* p) { return *(const f32x4*)p; }
__device__ inline f32x4 load4f(const __bf16* p) {
    bf16x4 v = *(const bf16x4*)p;
    f32x4 r;
#pragma unroll
    for (int i = 0; i < 4; ++i) r[i] = (float)v[i];
    return r;
}

// Async global->LDS, 16 bytes per lane (global_load_lds_dwordx4).
__device__ inline void gld_lds16(const void* g, void* l) {
    __builtin_amdgcn_global_load_lds(
        (const __attribute__((address_space(1))) unsigned int*)g,
        (__attribute__((address_space(3))) unsigned int*)l, 16, 0, 0);
}

// ===========================================================================
// 128x128 BK=64 tile machinery (shared by all GEMMs). XOR-swizzled LDS tile:
// LDS chunk (row, j) holds GLOBAL chunk (row, j ^ (row&7)); global source is
// pre-swizzled so the LDS destination stays linear (global_load_lds rule).
// ===========================================================================
template <typename T>
__device__ inline void stage_tile(const T* __restrict__ G, int ld, __bf16* s, int tid)
{
    const int r  = tid >> 3;                          // 0..31
    const int co = ((tid & 7) ^ (r & 7)) * 8;         // swizzled source column
    if constexpr (sizeof(T) == 2) {
        __bf16* dst = s + (tid >> 6) * 512;           // wave-uniform base
#pragma unroll
        for (int c = 0; c < 4; ++c)
            gld_lds16(G + (long)(c * 32 + r) * ld + co, dst + c * 2048);
    } else {
#pragma unroll
        for (int c = 0; c < 4; ++c)
            *(bf16x8*)(s + c * 2048 + tid * 8) = load8cvt(G + (long)(c * 32 + r) * ld + co);
    }
}

__device__ inline bf16x8 frag_read(const __bf16* s, int row, int c)
{
    return *(const bf16x8*)&s[row * 64 + ((c ^ (row & 7)) * 8)];
}

__device__ inline void mfma_ktile(const __bf16* __restrict__ sa,
                                  const __bf16* __restrict__ sb,
                                  int wm, int wn, int l15, int quad,
                                  f32x4 (&acc)[4][4])
{
#pragma unroll
    for (int kk = 0; kk < 64; kk += 32) {
        const int c8 = quad + (kk >> 3);
        bf16x8 af[4], bf[4];
#pragma unroll
        for (int i = 0; i < 4; ++i)
            af[i] = frag_read(sa, wm + i * 16 + l15, c8);
#pragma unroll
        for (int j = 0; j < 4; ++j)
            bf[j] = frag_read(sb, wn + j * 16 + l15, c8);
#pragma unroll
        for (int i = 0; i < 4; ++i)
#pragma unroll
            for (int j = 0; j < 4; ++j)
                acc[i][j] = __builtin_amdgcn_mfma_f32_16x16x32_bf16(af[i], bf[j], acc[i][j], 0, 0, 0);
    }
}

// ===========================================================================
// Projection GEMM (R1 double-buffered structure — best measured: 101.4 us
// fused; now launched as 3x512-block dispatches, z=0 each, for per-kernel
// rocprof visibility). vtmask bit z => transposed scatter-store vT[b][n][s].
// ===========================================================================
struct Proj3 {
    const void* A[3];
    const void* W[3];
    const float* bias[3];
    __bf16* C[3];
    int vtmask;
};

template <typename TA, typename TW>
__global__ __launch_bounds__(256) void gemm_proj(Proj3 p)
{
    __shared__ __bf16 sA[2][128 * 64];
    __shared__ __bf16 sB[2][128 * 64];

    const int tid = threadIdx.x;
    const int L = blockIdx.x;
    const int per = gridDim.x >> 3;
    const int wrk = (L & 7) * per + (L >> 3);
    const int n0 = (wrk & 7) * 128;
    const int m0 = ((wrk >> 3) & 63) * 128;
    const int z  = wrk >> 9;
    const bool vt = (p.vtmask >> z) & 1;

    const TA* Ag = (const TA*)p.A[z] + (long)m0 * HD;
    const TW* Wg = (const TW*)p.W[z] + (long)n0 * HD;
    const float* bias = p.bias[z];
    __bf16* C = p.C[z];

    const int lane = tid & 63;
    const int l15  = lane & 15;
    const int quad = lane >> 4;
    const int wave = tid >> 6;
    const int wm = (wave >> 1) * 64;
    const int wn = (wave & 1) * 64;

    f32x4 acc[4][4];
    const f32x4 zero = {0.f, 0.f, 0.f, 0.f};
#pragma unroll
    for (int i = 0; i < 4; ++i)
#pragma unroll
        for (int j = 0; j < 4; ++j) acc[i][j] = zero;

    stage_tile(Ag, HD, sA[0], tid);
    stage_tile(Wg, HD, sB[0], tid);
    __syncthreads();

    int cur = 0;
    for (int kc = 0; kc < HD; kc += 64) {
        const int nxt = kc + 64;
        if (nxt < HD) {                       // issue next tile's loads first
            stage_tile(Ag + nxt, HD, sA[cur ^ 1], tid);
            stage_tile(Wg + nxt, HD, sB[cur ^ 1], tid);
        }
        mfma_ktile(sA[cur], sB[cur], wm, wn, l15, quad, acc);
        __syncthreads();
        cur ^= 1;
    }

#pragma unroll
    for (int j = 0; j < 4; ++j) {
        const int col = n0 + wn + j * 16 + l15;
        const float bv = bias[col];
#pragma unroll
        for (int i = 0; i < 4; ++i) {
#pragma unroll
            for (int r = 0; r < 4; ++r) {
                const int row = m0 + wm + i * 16 + quad * 4 + r;
                const float v = acc[i][j][r] + bv;
                if (vt) {
                    C[(((long)(row >> 11) * HD) + col) * SEQ + (row & (SEQ - 1))] = (__bf16)v;
                } else {
                    C[(long)row * HD + col] = (__bf16)v;
                }
            }
        }
    }
}

// ---------------------------------------------------------------------------
// Scores GEMM, [t][s] layout: Et[t][s] = exp(<q_t,k_s>*alpha) for s<=t, else 0.
// A=qp (rows t), B=kp (rows s). TRI blocks: m0 = tb*128 (t) >= n0 = sb*128 (s).
// Row-sums (softmax denominators, per t) accumulated via shfl-reduce + atomics.
// ---------------------------------------------------------------------------
template <typename OutT>
__global__ __launch_bounds__(256) void gemm_sc(
    const __bf16* __restrict__ A, const __bf16* __restrict__ B,
    OutT* __restrict__ C, float* __restrict__ gsum, float alpha)
{
    __shared__ __bf16 s1[2][128 * 64];
    __shared__ __bf16 s2[2][128 * 64];
    __shared__ float csum[128];

    const int tid = threadIdx.x;
    const int L = blockIdx.x;
    const int per = gridDim.x >> 3;
    const int wrk = (L & 7) * per + (L >> 3);
    const int Lt = wrk % 136;
    const int z  = wrk / 136;
    int tb = (int)((sqrtf(8.f * Lt + 1.f) - 1.f) * 0.5f);
    while ((tb + 1) * (tb + 2) / 2 <= Lt) ++tb;
    while (tb * (tb + 1) / 2 > Lt) --tb;
    const int sb = Lt - tb * (tb + 1) / 2;
    const int m0 = tb * 128;      // t (row), tb >= sb
    const int n0 = sb * 128;      // s (col)

    const __bf16* Ag = A + (long)z * SEQ * HD + (long)m0 * HD;
    const __bf16* Bg = B + (long)z * SEQ * HD + (long)n0 * HD;
    C += (long)z * SEQ * SEQ;
    gsum += (long)z * SEQ;
    if (tid < 128) csum[tid] = 0.f;    // visible after first __syncthreads

    const int lane = tid & 63, l15 = lane & 15, quad = lane >> 4;
    const int wave = tid >> 6;
    const int wm = (wave >> 1) * 64;
    const int wn = (wave & 1) * 64;

    f32x4 acc[4][4];
    const f32x4 zero = {0.f, 0.f, 0.f, 0.f};
#pragma unroll
    for (int i = 0; i < 4; ++i)
#pragma unroll
        for (int j = 0; j < 4; ++j) acc[i][j] = zero;

    stage_tile(Ag, HD, s1[0], tid);
    stage_tile(Bg, HD, s2[0], tid);
    __syncthreads();
    int cur = 0;
    for (int kc = 0; kc < HD; kc += 64) {
        const int nxt = kc + 64;
        if (nxt < HD) {
            stage_tile(Ag + nxt, HD, s1[cur ^ 1], tid);
            stage_tile(Bg + nxt, HD, s2[cur ^ 1], tid);
        }
        mfma_ktile(s1[cur], s2[cur], wm, wn, l15, quad, acc);
        __syncthreads();
        cur ^= 1;
    }

    float rsum[4][4];
#pragma unroll
    for (int i = 0; i < 4; ++i)
#pragma unroll
        for (int r = 0; r < 4; ++r) rsum[i][r] = 0.f;

#pragma unroll
    for (int j = 0; j < 4; ++j) {
        const int col = n0 + wn + j * 16 + l15;
#pragma unroll
        for (int i = 0; i < 4; ++i) {
#pragma unroll
            for (int r = 0; r < 4; ++r) {
                const int row = m0 + wm + i * 16 + quad * 4 + r;
                const float e = (col <= row) ? __expf(acc[i][j][r] * alpha) : 0.f;
                C[(long)row * SEQ + col] = (OutT)e;
                rsum[i][r] += e;
            }
        }
    }
#pragma unroll
    for (int i = 0; i < 4; ++i) {
#pragma unroll
        for (int r = 0; r < 4; ++r) {
            float v = rsum[i][r];
            v += __shfl_xor(v, 1); v += __shfl_xor(v, 2);
            v += __shfl_xor(v, 4); v += __shfl_xor(v, 8);
            if (l15 == 0) atomicAdd(&csum[wm + i * 16 + quad * 4 + r], v);
        }
    }
    __syncthreads();
    if (tid < 128) atomicAdd(&gsum[m0 + tid], csum[tid]);
}

// ---------------------------------------------------------------------------
// Context GEMM: C[t][h] = inv[t] * sum_{s<=t} Et[t][s] * vT[h][s].
// A=Et (lda=SEQ), B=vT (ldb=SEQ), causal K-limit Kend=m0+128, per-row scale
// from gsum in epilogue. m-block index goes through the pairing bijection
// 0,15,1,14,... so consecutively-dispatched blocks pair long+short K (each
// adjacent pair sums to a uniform 2176 K-rows) -> balanced CU residency.
// ---------------------------------------------------------------------------
__global__ __launch_bounds__(256) void gemm_ctx(
    const __bf16* __restrict__ A, const __bf16* __restrict__ B,
    float* __restrict__ C, const float* __restrict__ gsum)
{
    __shared__ __bf16 s1[2][128 * 64];
    __shared__ __bf16 s2[2][128 * 64];
    __shared__ float rs[128];

    const int tid = threadIdx.x;
    const int L = blockIdx.x;
    const int per = gridDim.x >> 3;
    const int wrk = (L & 7) * per + (L >> 3);
    const int n0 = (wrk & 7) * 128;          // h
    const int q  = (wrk >> 3) & 15;
    const int mb = (q & 1) ? (15 - (q >> 1)) : (q >> 1);   // 0,15,1,14,...
    const int m0 = mb * 128;                 // t
    const int z  = wrk >> 7;

    const __bf16* Ag = A + (long)z * SEQ * SEQ + (long)m0 * SEQ;
    const __bf16* Bg = B + (long)z * HD * SEQ + (long)n0 * SEQ;
    C += (long)z * SEQ * HD;
    if (tid < 128) rs[tid] = gsum[(long)z * SEQ + m0 + tid];

    const int lane = tid & 63, l15 = lane & 15, quad = lane >> 4;
    const int wave = tid >> 6;
    const int wm = (wave >> 1) * 64;
    const int wn = (wave & 1) * 64;

    f32x4 acc[4][4];
    const f32x4 zero = {0.f, 0.f, 0.f, 0.f};
#pragma unroll
    for (int i = 0; i < 4; ++i)
#pragma unroll
        for (int j = 0; j < 4; ++j) acc[i][j] = zero;

    const int Kend = m0 + 128;

    stage_tile(Ag, SEQ, s1[0], tid);
    stage_tile(Bg, SEQ, s2[0], tid);
    __syncthreads();
    int cur = 0;
    for (int kc = 0; kc < Kend; kc += 64) {
        const int nxt = kc + 64;
        if (nxt < Kend) {
            stage_tile(Ag + nxt, SEQ, s1[cur ^ 1], tid);
            stage_tile(Bg + nxt, SEQ, s2[cur ^ 1], tid);
        }
        mfma_ktile(s1[cur], s2[cur], wm, wn, l15, quad, acc);
        __syncthreads();
        cur ^= 1;
    }

    float invr[4][4];
#pragma unroll
    for (int i = 0; i < 4; ++i)
#pragma unroll
        for (int r = 0; r < 4; ++r)
            invr[i][r] = 1.0f / rs[wm + i * 16 + quad * 4 + r];

#pragma unroll
    for (int j = 0; j < 4; ++j) {
        const int col = n0 + wn + j * 16 + l15;
#pragma unroll
        for (int i = 0; i < 4; ++i) {
#pragma unroll
            for (int r = 0; r < 4; ++r) {
                const int row = m0 + wm + i * 16 + quad * 4 + r;
                C[(long)row * HD + col] = acc[i][j][r] * invr[i][r];
            }
        }
    }
}

// ---------------------------------------------------------------------------
// Emit f32 attention output: Out[s][t] = Et[t][s] * inv[t]. 128x128 per block
// as 4 64x64 subtiles through PING-PONG LDS buffers: {STORE(k) || LOAD(k+1)}
// between barriers — 4 syncs instead of 8, and subtile k+1's global reads
// overlap subtile k's transpose-store. WAR-safe: LOAD(k+2) writes buf(k&1)
// only after the barrier that retired STORE(k)'s reads of that buffer.
// ---------------------------------------------------------------------------
__global__ __launch_bounds__(256) void emit_attn(
    const __bf16* __restrict__ Et, float* __restrict__ Out,
    const float* __restrict__ csum)
{
    __shared__ float tile[2][64][68];
    const int b = blockIdx.z;
    const int t0 = blockIdx.x * 128;
    const int s0 = blockIdx.y * 128;
    const __bf16* Eb = Et + (long)b * SEQ * SEQ;
    float* Ob = Out + (long)b * SEQ * SEQ;
    const int tid = threadIdx.x;

    if (s0 > t0 + 127) {     // fully masked: zero-fill f32 output
        const f32x4 z4 = {0.f, 0.f, 0.f, 0.f};
        const int c4 = (tid & 31) * 4;
        for (int r = tid >> 5; r < 128; r += 8)
            *(f32x4*)&Ob[(long)(s0 + r) * SEQ + t0 + c4] = z4;
        return;
    }

    const int c4 = (tid & 15) * 4;      // load-phase column group
    const int rr = tid >> 4;            // load-phase row within 16-chunk
    const int sl = tid >> 2;            // store-phase s-local row
    const int t4 = (tid & 3) * 4;       // store-phase col cluster

    auto LOAD = [&](int k, int buf) {
        const int tt = t0 + (k >> 1) * 64, ss = s0 + (k & 1) * 64;
#pragma unroll
        for (int r0 = 0; r0 < 64; r0 += 16) {
            const int tl = r0 + rr;
            const float inv = 1.0f / csum[(long)b * SEQ + tt + tl];
            f32x4 e = load4f(&Eb[(long)(tt + tl) * SEQ + ss + c4]);
#pragma unroll
            for (int kk = 0; kk < 4; ++kk) tile[buf][tl][c4 + kk] = e[kk] * inv;
        }
    };
    auto STORE = [&](int k, int buf) {
        const int tt = t0 + (k >> 1) * 64, ss = s0 + (k & 1) * 64;
#pragma unroll
        for (int qq = 0; qq < 4; ++qq) {
            f32x4 ov;
#pragma unroll
            for (int kk = 0; kk < 4; ++kk) ov[kk] = tile[buf][qq * 16 + t4 + kk][sl];
            *(f32x4*)&Ob[(long)(ss + sl) * SEQ + tt + qq * 16 + t4] = ov;
        }
    };

    LOAD(0, 0);
    __syncthreads();
    STORE(0, 0); LOAD(1, 1);
    __syncthreads();
    STORE(1, 1); LOAD(2, 0);
    __syncthreads();
    STORE(2, 0); LOAD(3, 1);
    __syncthreads();
    STORE(3, 1);
}

// ===========================================================================
// Legacy kernels (mid / fallback workspace paths) — unchanged semantics.
// ===========================================================================
template <bool TRI, bool CKLIM, bool EXPSUM, typename OutT>
__global__ __launch_bounds__(256) void gemm_bt(
    const __bf16* __restrict__ A, long strideA, int lda,
    const __bf16* __restrict__ B, long strideB, int ldb,
    OutT* __restrict__ C, long strideC, int ldc,
    float* __restrict__ gsum,
    int K, float alpha)
{
    __shared__ __bf16 sA[2][128 * 64];
    __shared__ __bf16 sB[2][128 * 64];
    __shared__ float csum[128];

    const int tid = threadIdx.x;
    const int L = blockIdx.x;
    const int per = gridDim.x >> 3;
    const int wrk = (L & 7) * per + (L >> 3);
    int n0, m0, z;
    if (TRI) {
        const int Lt = wrk % 136;
        z = wrk / 136;
        int tb = (int)((sqrtf(8.f * Lt + 1.f) - 1.f) * 0.5f);
        while ((tb + 1) * (tb + 2) / 2 <= Lt) ++tb;
        while (tb * (tb + 1) / 2 > Lt) --tb;
        const int sb = Lt - tb * (tb + 1) / 2;
        n0 = tb * 128;
        m0 = sb * 128;
    } else {
        n0 = (wrk & 7) * 128;
        m0 = ((wrk >> 3) & 15) * 128;
        z  = wrk >> 7;
    }

    const __bf16* Ag = A + (long)z * strideA + (long)m0 * lda;
    const __bf16* Bg = B + (long)z * strideB + (long)n0 * ldb;
    C += (long)z * strideC;
    if (EXPSUM) {
        gsum += (long)z * SEQ;
        if (tid < 128) csum[tid] = 0.f;
    }

    const int lane = tid & 63;
    const int l15  = lane & 15;
    const int quad = lane >> 4;
    const int wave = tid >> 6;
    const int wm = (wave >> 1) * 64;
    const int wn = (wave & 1) * 64;

    f32x4 acc[4][4];
    const f32x4 zero = {0.f, 0.f, 0.f, 0.f};
#pragma unroll
    for (int i = 0; i < 4; ++i)
#pragma unroll
        for (int j = 0; j < 4; ++j) acc[i][j] = zero;

    const int Kend = CKLIM ? min(K, m0 + 128) : K;

    stage_tile(Ag, lda, sA[0], tid);
    stage_tile(Bg, ldb, sB[0], tid);
    __syncthreads();

    int cur = 0;
    for (int kc = 0; kc < Kend; kc += 64) {
        const int nxt = kc + 64;
        if (nxt < Kend) {
            stage_tile(Ag + nxt, lda, sA[cur ^ 1], tid);
            stage_tile(Bg + nxt, ldb, sB[cur ^ 1], tid);
        }
        mfma_ktile(sA[cur], sB[cur], wm, wn, l15, quad, acc);
        __syncthreads();
        cur ^= 1;
    }

#pragma unroll
    for (int j = 0; j < 4; ++j) {
        const int col = n0 + wn + j * 16 + l15;
        float part = 0.f;
#pragma unroll
        for (int i = 0; i < 4; ++i) {
#pragma unroll
            for (int r = 0; r < 4; ++r) {
                const int row = m0 + wm + i * 16 + quad * 4 + r;
                float v = acc[i][j][r] * alpha;
                if (EXPSUM) {
                    v = __expf(v);
                    if (row <= col) part += v;
                }
                C[(long)row * ldc + col] = (OutT)v;
            }
        }
        if (EXPSUM) atomicAdd(&csum[wn + j * 16 + l15], part);
    }
    if (EXPSUM) {
        __syncthreads();
        if (tid < 128) atomicAdd(&gsum[n0 + tid], csum[tid]);
    }
}

template <typename ET>
__global__ __launch_bounds__(256) void scale_emit(
    const ET* __restrict__ E, float* __restrict__ Out,
    const float* __restrict__ csum, __bf16* __restrict__ AT)
{
    __shared__ __bf16 tile[64][65];
    const int b = blockIdx.z;
    const int t0 = blockIdx.x * 128;
    const int s0 = blockIdx.y * 128;
    const ET* Eb = E + (long)b * SEQ * SEQ;
    float* Ob = Out + (long)b * SEQ * SEQ;
    __bf16* Ab = AT + (long)b * SEQ * SEQ;
    const int tid = threadIdx.x;

    if (s0 > t0 + 127) {
        const f32x4 z4 = {0.f, 0.f, 0.f, 0.f};
        const int c4 = (tid & 31) * 4;
        for (int r = tid >> 5; r < 128; r += 8)
            *(f32x4*)&Ob[(long)(s0 + r) * SEQ + t0 + c4] = z4;
        return;
    }

#pragma unroll
    for (int ds = 0; ds < 2; ++ds) {
#pragma unroll
        for (int dt = 0; dt < 2; ++dt) {
            const int ss = s0 + ds * 64, tt = t0 + dt * 64;
            const int c4 = (tid & 15) * 4;
            const int tcol = tt + c4;
            const f32x4 sv = *(const f32x4*)&csum[(long)b * SEQ + tcol];
            f32x4 inv;
#pragma unroll
            for (int k = 0; k < 4; ++k) inv[k] = 1.0f / sv[k];
#pragma unroll
            for (int r0 = 0; r0 < 64; r0 += 16) {
                const int s = ss + r0 + (tid >> 4);
                f32x4 e = load4f(&Eb[(long)s * SEQ + tcol]);
                f32x4 p;
#pragma unroll
                for (int k = 0; k < 4; ++k)
                    p[k] = (s <= tcol + k) ? e[k] * inv[k] : 0.f;
                *(f32x4*)&Ob[(long)s * SEQ + tcol] = p;
#pragma unroll
                for (int k = 0; k < 4; ++k)
                    tile[r0 + (tid >> 4)][c4 + k] = (__bf16)p[k];
            }
            __syncthreads();
            const int tr = tid >> 2;
            const int sc = (tid & 3) * 16;
            __bf16 v[16];
#pragma unroll
            for (int jj = 0; jj < 16; ++jj) v[jj] = tile[sc + jj][tr];
            *(bf16x8*)&Ab[(long)(tt + tr) * SEQ + ss + sc]     = *(bf16x8*)v;
            *(bf16x8*)&Ab[(long)(tt + tr) * SEQ + ss + sc + 8] = *(bf16x8*)(v + 8);
            __syncthreads();
        }
    }
}

// ---------------------------------------------------------------------------
// Batched f32 -> bf16 convert: up to 6 jobs in one dispatch.
// ---------------------------------------------------------------------------
struct CvtJob { const float* in; __bf16* out; int nblk; };
struct Cvt6 { CvtJob j[6]; };
__global__ __launch_bounds__(256) void cvt_bf16(Cvt6 c)
{
    const CvtJob jb = c.j[blockIdx.y];
    if ((int)blockIdx.x >= jb.nblk) return;
    const long i = ((long)blockIdx.x * 256 + threadIdx.x) * 8;
    *(bf16x8*)&jb.out[i] = load8cvt(&jb.in[i]);
}

// ---------------------------------------------------------------------------
extern "C" void kernel_launch(void* const* d_in, const int* in_sizes, int n_in,
                              void* d_out, int out_size, void* d_ws, size_t ws_size,
                              hipStream_t stream)
{
    const float* queries = (const float*)d_in[0];
    const float* keys    = (const float*)d_in[1];
    const float* values  = (const float*)d_in[2];
    const float* Wq = (const float*)d_in[3];
    const float* bq = (const float*)d_in[4];
    const float* Wk = (const float*)d_in[5];
    const float* bk = (const float*)d_in[6];
    const float* Wv = (const float*)d_in[7];
    const float* bv = (const float*)d_in[8];

    const long tokens = (long)NB * SEQ;           // 8192
    const long pe = tokens * HD;                  // elems per 16 MiB buffer
    const size_t SLOT = (size_t)pe * sizeof(__bf16);   // 16 MiB
    const int ABLK = (int)(pe / 2048);            // 4096 cvt blocks per activation
    const int WBLK = WEL / 2048;                  // 512 cvt blocks per weight

    float* outCtx  = (float*)d_out;               // [4][2048][1024] f32
    float* outAttn = outCtx + tokens * HD;        // [4][2048][2048] f32
    __bf16* wb = (__bf16*)outAttn;                // bf16 weights: dead-at-start
    __bf16* Wqb = wb, *Wkb = wb + WEL, *Wvb = wb + 2 * WEL;

    const dim3 blk(256);
    char* w = (char*)d_ws;
    __bf16 *qp, *kp, *vT;

    if (ws_size >= 6 * SLOT) {
        // [xq][xk][xv][qp][kp][vT]; after proj: Et bf16 -> slots 0-1,
        // colsum -> slot 2 (xv dead), vT slot 5 stays live.
        __bf16* xq = (__bf16*)w;
        __bf16* xk = (__bf16*)(w + SLOT);
        __bf16* xv = (__bf16*)(w + 2 * SLOT);
        qp = (__bf16*)(w + 3 * SLOT);
        kp = (__bf16*)(w + 4 * SLOT);
        vT = (__bf16*)(w + 5 * SLOT);
        __bf16* Ebf = (__bf16*)w;
        float* colsum = (float*)(w + 2 * SLOT);

        Cvt6 cv = {{{queries, xq, ABLK}, {keys, xk, ABLK}, {values, xv, ABLK},
                    {Wq, Wqb, WBLK}, {Wk, Wkb, WBLK}, {Wv, Wvb, WBLK}}};
        cvt_bf16<<<dim3(ABLK, 6), blk, 0, stream>>>(cv);
        // 3 x 512-block dispatches (z=0 each): identical work to the fused
        // 1536-block launch, but each shows up separately in rocprof.
        Proj3 pq = {{xq, nullptr, nullptr}, {Wqb, nullptr, nullptr},
                    {bq, nullptr, nullptr}, {qp, nullptr, nullptr}, 0};
        gemm_proj<__bf16, __bf16><<<dim3(512), blk, 0, stream>>>(pq);
        Proj3 pk = {{xk, nullptr, nullptr}, {Wkb, nullptr, nullptr},
                    {bk, nullptr, nullptr}, {kp, nullptr, nullptr}, 0};
        gemm_proj<__bf16, __bf16><<<dim3(512), blk, 0, stream>>>(pk);
        Proj3 pv = {{xv, nullptr, nullptr}, {Wvb, nullptr, nullptr},
                    {bv, nullptr, nullptr}, {vT, nullptr, nullptr}, 1};
        gemm_proj<__bf16, __bf16><<<dim3(512), blk, 0, stream>>>(pv);

        hipMemsetAsync(colsum, 0, (size_t)NB * SEQ * sizeof(float), stream);
        // Et[b][t][s] = exp(<q_t,k_s>/32) masked; rowsums into colsum
        gemm_sc<__bf16><<<dim3(544), blk, 0, stream>>>(qp, kp, Ebf, colsum, 0.03125f);
        // f32 attn output (transposed, normalized)
        emit_attn<<<dim3(SEQ / 128, SEQ / 128, NB), blk, 0, stream>>>(
            Ebf, outAttn, colsum);
        // context with per-row normalization in epilogue
        gemm_ctx<<<dim3(512), blk, 0, stream>>>(Ebf, vT, outCtx, colsum);
    } else if (ws_size >= 4 * SLOT) {
        // legacy mid path: [x0][qp][kp][x1->vT]; attnT aliases x0+qp;
        // E stays f32 in outAttn (in-place scale_emit).
        float* colsum = outCtx;
        hipMemsetAsync(colsum, 0, (size_t)NB * SEQ * sizeof(float), stream);
        __bf16* x0 = (__bf16*)w;
        qp = (__bf16*)(w + SLOT);
        kp = (__bf16*)(w + 2 * SLOT);
        __bf16* x1 = (__bf16*)(w + 3 * SLOT);
        vT = x1;
        __bf16* attnT = (__bf16*)d_ws;

        Cvt6 cv = {{{queries, x0, ABLK}, {keys, x1, ABLK},
                    {Wq, Wqb, WBLK}, {Wk, Wkb, WBLK}, {Wv, Wvb, WBLK},
                    {nullptr, nullptr, 0}}};
        cvt_bf16<<<dim3(ABLK, 5), blk, 0, stream>>>(cv);
        Proj3 pqk = {{x0, x1, nullptr}, {Wqb, Wkb, nullptr}, {bq, bk, nullptr},
                     {qp, kp, nullptr}, 0};
        gemm_proj<__bf16, __bf16><<<dim3(512 * 2), blk, 0, stream>>>(pqk);
        Cvt6 cvv = {{{values, x0, ABLK}, {nullptr, nullptr, 0}, {nullptr, nullptr, 0},
                     {nullptr, nullptr, 0}, {nullptr, nullptr, 0}, {nullptr, nullptr, 0}}};
        cvt_bf16<<<dim3(ABLK, 1), blk, 0, stream>>>(cvv);
        Proj3 pv = {{x0, nullptr, nullptr}, {Wvb, nullptr, nullptr},
                    {bv, nullptr, nullptr}, {vT, nullptr, nullptr}, 1};
        gemm_proj<__bf16, __bf16><<<dim3(512), blk, 0, stream>>>(pv);

        gemm_bt<true, false, true, float><<<dim3(544), blk, 0, stream>>>(
            kp, (long)SEQ * HD, HD, qp, (long)SEQ * HD, HD,
            outAttn, (long)SEQ * SEQ, SEQ, colsum, HD, 0.03125f);
        scale_emit<float><<<dim3(SEQ / 128, SEQ / 128, NB), blk, 0, stream>>>(
            outAttn, outAttn, colsum, attnT);
        gemm_bt<false, true, false, float><<<dim3(512), blk, 0, stream>>>(
            attnT, (long)SEQ * SEQ, SEQ, vT, (long)HD * SEQ, SEQ,
            outCtx, (long)SEQ * HD, HD, nullptr, SEQ, 1.0f);
    } else {
        // fallback: f32-staged operands straight from inputs; [qp][kp][vT]
        float* colsum = outCtx;
        hipMemsetAsync(colsum, 0, (size_t)NB * SEQ * sizeof(float), stream);
        qp = (__bf16*)w;
        kp = (__bf16*)(w + SLOT);
        vT = (__bf16*)(w + 2 * SLOT);
        __bf16* attnT = (__bf16*)d_ws;
        Proj3 pj = {{queries, keys, values}, {Wq, Wk, Wv}, {bq, bk, bv},
                    {qp, kp, vT}, 4};
        gemm_proj<float, float><<<dim3(512 * 3), blk, 0, stream>>>(pj);

        gemm_bt<true, false, true, float><<<dim3(544), blk, 0, stream>>>(
            kp, (long)SEQ * HD, HD, qp, (long)SEQ * HD, HD,
            outAttn, (long)SEQ * SEQ, SEQ, colsum, HD, 0.03125f);
        scale_emit<float><<<dim3(SEQ / 128, SEQ / 128, NB), blk, 0, stream>>>(
            outAttn, outAttn, colsum, attnT);
        gemm_bt<false, true, false, float><<<dim3(512), blk, 0, stream>>>(
            attnT, (long)SEQ * SEQ, SEQ, vT, (long)HD * SEQ, SEQ,
            outCtx, (long)SEQ * HD, HD, nullptr, SEQ, 1.0f);
    }
}